// Round 3
// baseline (8376.085 us; speedup 1.0000x reference)
//
#include <hip/hip_runtime.h>
#include <math.h>

// ---------------- problem constants ----------------
namespace {
constexpr int NB = 4;
constexpr int SEQ = 128;
constexpr int TH_ = 120;
constexpr int NSTEP = 8;
constexpr int DMODEL = 512;
constexpr int NHEAD = 8;
constexpr int DHEAD = 64;
constexpr int DFFN = 2048;
constexpr int DIN = 32;
constexpr int MROWS = NB*SEQ;   // 512 flattened rows
constexpr float SCALE_EMB = 22.627416997969522f; // sqrt(512)
constexpr float LN_EPS = 1e-5f;
constexpr float NEGF = -3.4028234663852886e38f;  // jnp.finfo(f32).min
constexpr float PE_C = -0.017988946039015984f;   // -ln(10000)/512
constexpr unsigned NBLK = 128;  // persistent grid: 128 blocks < 256 CUs -> co-resident
}

using short8 = __attribute__((ext_vector_type(8))) short;
using f32x4  = __attribute__((ext_vector_type(4))) float;
using u32x2  = __attribute__((ext_vector_type(2))) unsigned int;

// ---------------- grid barrier state (device global; zeroed by init_misc each launch) ----
__device__ unsigned g_cnt = 0;

// ---------------- device helpers ----------------
__device__ __forceinline__ float wave_sum(float v){
#pragma unroll
  for(int off=32;off;off>>=1) v += __shfl_xor(v,off,64);
  return v;
}
__device__ __forceinline__ float blk_sum(float v, float* scr){
  v = wave_sum(v);
  __syncthreads();
  if((threadIdx.x&63)==0) scr[threadIdx.x>>6]=v;
  __syncthreads();
  return scr[0]+scr[1]+scr[2]+scr[3];
}
__device__ __forceinline__ float gelu_t(float x){
  float t = 0.7978845608028654f*(x + 0.044715f*x*x*x);
  return 0.5f*x*(1.0f + tanhf(t));
}
__device__ __forceinline__ float pe_val(int t, int d){
  float div = expf((float)(d & ~1) * PE_C);
  float a = (float)t * div;
  return (d & 1) ? cosf(a) : sinf(a);
}
__device__ __forceinline__ unsigned short f2b(float f){
  union { float f; unsigned u; } c; c.f = f;
  unsigned u = c.u + 0x7FFFu + ((c.u>>16)&1u);
  return (unsigned short)(u>>16);
}
__device__ __forceinline__ short8 pack8(const float* f){
  short8 s;
#pragma unroll
  for(int i=0;i<8;i++) s[i] = (short)f2b(f[i]);
  return s;
}

// ---------------- MALL-direct (cross-XCD coherent, L2-bypass) access helpers -----------
// sc0 sc1 = coherence-point access: stores write through to MALL (globally visible once
// vmcnt retires), loads read the MALL (never a stale per-XCD L2 line). Weights stay on
// the normal cached path and remain L2-hot because we never invalidate L2.
__device__ __forceinline__ void ld_a32(const unsigned short* p, short8& a0, short8& a1){
  asm volatile("global_load_dwordx4 %0, %2, off sc0 sc1\n\t"
               "global_load_dwordx4 %1, %2, off offset:16 sc0 sc1\n\t"
               "s_waitcnt vmcnt(0)"
               : "=&v"(a0), "=&v"(a1) : "v"(p) : "memory");
}
__device__ __forceinline__ void ld_f4x4(const float* p, f32x4& a, f32x4& b, f32x4& c, f32x4& d){
  asm volatile("global_load_dwordx4 %0, %4, off sc0 sc1\n\t"
               "global_load_dwordx4 %1, %4, off offset:16 sc0 sc1\n\t"
               "global_load_dwordx4 %2, %4, off offset:32 sc0 sc1\n\t"
               "global_load_dwordx4 %3, %4, off offset:48 sc0 sc1\n\t"
               "s_waitcnt vmcnt(0)"
               : "=&v"(a),"=&v"(b),"=&v"(c),"=&v"(d) : "v"(p) : "memory");
}
__device__ __forceinline__ void ld_f4x8(const float* p0,const float* p1,const float* p2,const float* p3,
                                        f32x4& a0, f32x4& a1, f32x4& b0, f32x4& b1,
                                        f32x4& c0, f32x4& c1, f32x4& d0, f32x4& d1){
  asm volatile(
    "global_load_dwordx4 %0, %8, off sc0 sc1\n\t"
    "global_load_dwordx4 %1, %8, off offset:16 sc0 sc1\n\t"
    "global_load_dwordx4 %2, %9, off sc0 sc1\n\t"
    "global_load_dwordx4 %3, %9, off offset:16 sc0 sc1\n\t"
    "global_load_dwordx4 %4, %10, off sc0 sc1\n\t"
    "global_load_dwordx4 %5, %10, off offset:16 sc0 sc1\n\t"
    "global_load_dwordx4 %6, %11, off sc0 sc1\n\t"
    "global_load_dwordx4 %7, %11, off offset:16 sc0 sc1\n\t"
    "s_waitcnt vmcnt(0)"
    : "=&v"(a0),"=&v"(a1),"=&v"(b0),"=&v"(b1),"=&v"(c0),"=&v"(c1),"=&v"(d0),"=&v"(d1)
    : "v"(p0),"v"(p1),"v"(p2),"v"(p3) : "memory");
}
__device__ __forceinline__ void ld_f4g4(const float* p0,const float* p1,const float* p2,const float* p3,
                                        f32x4& a, f32x4& b, f32x4& c, f32x4& d){
  asm volatile(
    "global_load_dwordx4 %0, %4, off sc0 sc1\n\t"
    "global_load_dwordx4 %1, %5, off sc0 sc1\n\t"
    "global_load_dwordx4 %2, %6, off sc0 sc1\n\t"
    "global_load_dwordx4 %3, %7, off sc0 sc1\n\t"
    "s_waitcnt vmcnt(0)"
    : "=&v"(a),"=&v"(b),"=&v"(c),"=&v"(d)
    : "v"(p0),"v"(p1),"v"(p2),"v"(p3) : "memory");
}
__device__ __forceinline__ void ld_f4g2(const float* p0,const float* p1, f32x4& a, f32x4& b){
  asm volatile(
    "global_load_dwordx4 %0, %2, off sc0 sc1\n\t"
    "global_load_dwordx4 %1, %3, off sc0 sc1\n\t"
    "s_waitcnt vmcnt(0)"
    : "=&v"(a),"=&v"(b) : "v"(p0),"v"(p1) : "memory");
}
// 4 scalar loads at row-stride DMODEL (2048B): rows r..r+3 of column n
__device__ __forceinline__ void ld_resid4(const float* p, float& a,float& b,float& c,float& d){
  asm volatile(
    "global_load_dword %0, %4, off sc0 sc1\n\t"
    "global_load_dword %1, %4, off offset:2048 sc0 sc1\n\t"
    "global_load_dword %2, %5, off sc0 sc1\n\t"
    "global_load_dword %3, %5, off offset:2048 sc0 sc1\n\t"
    "s_waitcnt vmcnt(0)"
    : "=&v"(a),"=&v"(b),"=&v"(c),"=&v"(d)
    : "v"(p), "v"(p+2*DMODEL) : "memory");
}
__device__ __forceinline__ void st_f1(float* p, float v){
  asm volatile("global_store_dword %0, %1, off sc0 sc1" :: "v"(p), "v"(v) : "memory");
}
__device__ __forceinline__ void st_b16(unsigned short* p, unsigned short v){
  unsigned w32 = v;
  asm volatile("global_store_short %0, %1, off sc0 sc1" :: "v"(p), "v"(w32) : "memory");
}
__device__ __forceinline__ void st_u64(void* p, u32x2 v){
  asm volatile("global_store_dwordx2 %0, %1, off sc0 sc1" :: "v"(p), "v"(v) : "memory");
}

// grid barrier: drain own stores (write-ack => globally visible for sc0sc1 stores),
// block-barrier, relaxed arrive, relaxed spin. NO acquire/release fences -> L2 never
// invalidated -> weights stay L2-resident across all 176 barriers.
__device__ __forceinline__ void gsync(unsigned target){
  asm volatile("s_waitcnt vmcnt(0)" ::: "memory");
  __syncthreads();
  if(threadIdx.x==0){
    __hip_atomic_fetch_add(&g_cnt, 1u, __ATOMIC_RELAXED, __HIP_MEMORY_SCOPE_AGENT);
    while(__hip_atomic_load(&g_cnt, __ATOMIC_RELAXED, __HIP_MEMORY_SCOPE_AGENT) < target){
      __builtin_amdgcn_s_sleep(2);
    }
  }
  __syncthreads();
}

// ---------------- shared-memory union (one allocation reused by every stage) ----------
struct SmemG { unsigned short As[64][72]; unsigned short Bs[128][72];
               float mu[64]; float rs[64]; };                                     // 28.2 KB
struct SmemA { float kv[SEQ][DHEAD]; float wsm[32][132]; float qs[32][68]; };     // 58.4 KB
struct SmemC { float raw[DMODEL]; float ctx[DMODEL]; float scr[4]; };             //  4.1 KB
struct SmemR { float cur[DIN]; float gs[DFFN]; float dscr[DIN]; };                //  8.4 KB
union alignas(16) SmemU { SmemG g; SmemA a; SmemC c; SmemR r; };

// ---------------- one-time: convert all weights to bf16 ----------------
__global__ __launch_bounds__(256) void conv_w(const float* __restrict__ Wq,
                                              const float* __restrict__ Wk,
                                              const float* __restrict__ Wv,
                                              const float* __restrict__ Wo,
                                              const float* __restrict__ W1,
                                              const float* __restrict__ W2,
                                              unsigned short* __restrict__ dst){
  size_t base = ((size_t)blockIdx.x*256 + threadIdx.x)*8;
  if(base >= 12582912u) return;
  const float* src; size_t off;
  if(base < 1048576u){ src=Wq; off=base; }
  else if(base < 2097152u){ src=Wk; off=base-1048576u; }
  else if(base < 3145728u){ src=Wv; off=base-2097152u; }
  else if(base < 4194304u){ src=Wo; off=base-3145728u; }
  else if(base < 8388608u){ src=W1; off=base-4194304u; }
  else { src=W2; off=base-8388608u; }
  float4 a = *(const float4*)(src+off);
  float4 b = *(const float4*)(src+off+4);
  float f[8] = {a.x,a.y,a.z,a.w,b.x,b.y,b.z,b.w};
  *(short8*)(dst + base) = pack8(f);
}

// ---------------- h0 init (fp32 + bf16) ----------------
__global__ __launch_bounds__(256) void init_h0(const float* __restrict__ hist,
                                               const float* __restrict__ W_emb,
                                               const float* __restrict__ b_emb,
                                               float* __restrict__ h0,
                                               unsigned short* __restrict__ h0b){
  int bt = blockIdx.x;
  int b = bt >> 7, t = bt & 127;
  __shared__ float x[DIN];
  if(threadIdx.x < DIN)
    x[threadIdx.x] = (t < TH_) ? hist[((size_t)b*TH_ + t)*DIN + threadIdx.x] : 0.f;
  __syncthreads();
  for(int d = threadIdx.x; d < DMODEL; d += 256){
    float s = 0.f;
#pragma unroll 8
    for(int i=0;i<DIN;i++) s += W_emb[d*DIN+i]*x[i];
    float v = SCALE_EMB*(s + b_emb[d]) + pe_val(t,d);
    h0[(size_t)bt*DMODEL + d] = v;
    h0b[(size_t)bt*DMODEL + d] = f2b(v);
  }
}

// ---------------- M1 / cb1 / cur_x init (+ barrier reset) ----------------
__global__ __launch_bounds__(256) void init_misc(const float* __restrict__ Wr1,
                                                 const float* __restrict__ W_emb,
                                                 const float* __restrict__ b_emb,
                                                 const float* __restrict__ br1,
                                                 const float* __restrict__ hist,
                                                 float* __restrict__ M1,
                                                 float* __restrict__ cb1,
                                                 float* __restrict__ cur_x){
  if(blockIdx.x==0 && threadIdx.x==255) g_cnt = 0u;   // reset grid barrier each replay
  __shared__ float row[DMODEL];
  int j0 = blockIdx.x*8;
  for(int jj=0;jj<8;jj++){
    int j = j0+jj;
    for(int k=threadIdx.x;k<DMODEL;k+=256) row[k] = Wr1[(size_t)j*1024 + k];
    __syncthreads();
    if(threadIdx.x < DIN){
      int i = threadIdx.x; float s = 0.f;
      for(int k=0;k<DMODEL;k++) s += row[k]*W_emb[k*DIN+i];
      M1[j*DIN+i] = SCALE_EMB*s;
    } else if(threadIdx.x == DIN){
      float s=0.f;
      for(int k=0;k<DMODEL;k++) s += row[k]*b_emb[k];
      cb1[j] = br1[j] + SCALE_EMB*s;
    }
    __syncthreads();
  }
  if(blockIdx.x==0 && threadIdx.x<NB*DIN){
    int b = threadIdx.x>>5, i = threadIdx.x&31;
    cur_x[b*DIN+i] = hist[((size_t)b*TH_ + (TH_-1))*DIN + i];
  }
}

// ---------------- bf16 MFMA GEMM tile 64x128, 4 waves, with optional fused LN ----------
// ln_mode: 0 = none; 1 = A operand is LN(lnx)*g+b packed bf16 on the fly;
//          2 = epilogue residual is LN(lnx)*g+b.
// Activation traffic (A16 / lnx / resid / C outputs) is MALL-direct; weights cached.
__device__ __forceinline__ void gemm_body(int bx, int by, SmemG& S,
    const unsigned short* __restrict__ A16, int Ka,
    const unsigned short* __restrict__ Wa,
    const unsigned short* __restrict__ Wb,
    const unsigned short* __restrict__ Wc,
    const float* __restrict__ bias, const float* __restrict__ resid,
    const float* __restrict__ lnx, const float* __restrict__ lng,
    const float* __restrict__ lnbta, int ln_mode,
    float* __restrict__ Cf, unsigned short* __restrict__ Cb,
    int c_rs, int c_mode, int act)
{
  int n0 = bx*128;
  int m0 = by*64;
  int tid = threadIdx.x, w = tid>>6, ln = tid&63;

  const unsigned short* Wsrc; int nrow0;
  if(c_mode==2){ int which = n0>>9; Wsrc = (which==0?Wa:(which==1?Wb:Wc)); nrow0 = n0&511; }
  else { Wsrc = Wa; nrow0 = n0; }

  // ---- LN row-stats prologue (exact wave-per-row reduction -> bit-identical mu/rs) ----
  if(ln_mode){
    int l = tid&63;
    for(int rr=0;rr<16;rr+=4){
      int rw = w*16 + rr;
      const float* xp = lnx + (size_t)(m0+rw)*DMODEL + l*8;
      f32x4 xa0,xa1,xb0,xb1,xc0,xc1,xd0,xd1;
      ld_f4x8(xp, xp+DMODEL, xp+2*DMODEL, xp+3*DMODEL,
              xa0,xa1,xb0,xb1,xc0,xc1,xd0,xd1);
      f32x4 lo[4] = {xa0,xb0,xc0,xd0};
      f32x4 hi[4] = {xa1,xb1,xc1,xd1};
#pragma unroll
      for(int j=0;j<4;j++){
        float f[8];
#pragma unroll
        for(int i=0;i<4;i++){ f[i]=lo[j][i]; f[4+i]=hi[j][i]; }
        float s = 0.f;
#pragma unroll
        for(int i=0;i<8;i++) s += f[i];
        s = wave_sum(s);
        float mu = s*(1.f/DMODEL);
        float v2 = 0.f;
#pragma unroll
        for(int i=0;i<8;i++){ float d0=f[i]-mu; v2 += d0*d0; }
        v2 = wave_sum(v2);
        float rsv = rsqrtf(v2*(1.f/DMODEL) + LN_EPS);
        if(l==0){ S.mu[rw+j]=mu; S.rs[rw+j]=rsv; }
      }
    }
    __syncthreads();
  }

  f32x4 acc[4][2];
#pragma unroll
  for(int i=0;i<4;i++)
#pragma unroll
    for(int j=0;j<2;j++) acc[i][j] = (f32x4){0.f,0.f,0.f,0.f};

  int fr = ln&15, fq = (ln>>4)*8;
  int arow = tid>>2, akq = (tid&3)*16;
  int brow = tid>>1, bkq = (tid&1)*32;

  float amu=0.f, ars=0.f;
  if(ln_mode==1){ amu = S.mu[arow]; ars = S.rs[arow]; }

  for(int k0=0;k0<Ka;k0+=64){
    // B first: plain cached loads (weights, L2-hot)
    const unsigned short* bp = Wsrc + (size_t)(nrow0+brow)*Ka + k0 + bkq;
    short8 b0 = *(const short8*)bp;
    short8 b1 = *(const short8*)(bp+8);
    short8 b2 = *(const short8*)(bp+16);
    short8 b3 = *(const short8*)(bp+24);
    if(ln_mode==1){
      const float* fp = lnx + (size_t)(m0+arow)*DMODEL + k0 + akq;
      f32x4 t0,t1,t2,t3;
      ld_f4x4(fp, t0,t1,t2,t3);
      const float* gp = lng + k0 + akq;
      const float* cp = lnbta + k0 + akq;
      float4 g0 = *(const float4*)(gp);
      float4 g1 = *(const float4*)(gp+4);
      float4 g2 = *(const float4*)(gp+8);
      float4 g3 = *(const float4*)(gp+12);
      float4 c0 = *(const float4*)(cp);
      float4 c1 = *(const float4*)(cp+4);
      float4 c2 = *(const float4*)(cp+8);
      float4 c3 = *(const float4*)(cp+12);
      float tt[16], gg[16], cc[16];
#pragma unroll
      for(int i=0;i<4;i++){ tt[i]=t0[i]; tt[4+i]=t1[i]; tt[8+i]=t2[i]; tt[12+i]=t3[i]; }
      gg[0]=g0.x; gg[1]=g0.y; gg[2]=g0.z; gg[3]=g0.w;
      gg[4]=g1.x; gg[5]=g1.y; gg[6]=g1.z; gg[7]=g1.w;
      gg[8]=g2.x; gg[9]=g2.y; gg[10]=g2.z; gg[11]=g2.w;
      gg[12]=g3.x; gg[13]=g3.y; gg[14]=g3.z; gg[15]=g3.w;
      cc[0]=c0.x; cc[1]=c0.y; cc[2]=c0.z; cc[3]=c0.w;
      cc[4]=c1.x; cc[5]=c1.y; cc[6]=c1.z; cc[7]=c1.w;
      cc[8]=c2.x; cc[9]=c2.y; cc[10]=c2.z; cc[11]=c2.w;
      cc[12]=c3.x; cc[13]=c3.y; cc[14]=c3.z; cc[15]=c3.w;
      float o[16];
#pragma unroll
      for(int i=0;i<16;i++) o[i] = (tt[i]-amu)*ars*gg[i] + cc[i];
      *(short8*)&S.As[arow][akq]   = pack8(o);
      *(short8*)&S.As[arow][akq+8] = pack8(o+8);
    } else {
      short8 a0, a1;
      ld_a32(A16 + (size_t)(m0+arow)*Ka + k0 + akq, a0, a1);
      *(short8*)&S.As[arow][akq]   = a0;
      *(short8*)&S.As[arow][akq+8] = a1;
    }
    *(short8*)&S.Bs[brow][bkq]    = b0;
    *(short8*)&S.Bs[brow][bkq+8]  = b1;
    *(short8*)&S.Bs[brow][bkq+16] = b2;
    *(short8*)&S.Bs[brow][bkq+24] = b3;
    __syncthreads();
    short8 af[4][2], bf[2][2];
#pragma unroll
    for(int kf=0;kf<2;kf++){
#pragma unroll
      for(int rt=0;rt<4;rt++) af[rt][kf] = *(const short8*)&S.As[rt*16 + fr][kf*32 + fq];
#pragma unroll
      for(int ct=0;ct<2;ct++) bf[ct][kf] = *(const short8*)&S.Bs[32*w + ct*16 + fr][kf*32 + fq];
    }
#pragma unroll
    for(int kf=0;kf<2;kf++)
#pragma unroll
      for(int rt=0;rt<4;rt++)
#pragma unroll
        for(int ct=0;ct<2;ct++)
          acc[rt][ct] = __builtin_amdgcn_mfma_f32_16x16x32_bf16(af[rt][kf], bf[ct][kf], acc[rt][ct], 0, 0, 0);
    __syncthreads();
  }

#pragma unroll
  for(int rt=0;rt<4;rt++){
#pragma unroll
    for(int ct=0;ct<2;ct++){
      int n = n0 + 32*w + ct*16 + fr;
      int ri0 = rt*16 + (ln>>4)*4;
      int row0 = m0 + ri0;
      float rv[4] = {0.f,0.f,0.f,0.f};
      if(ln_mode==2)
        ld_resid4(lnx + (size_t)row0*DMODEL + n, rv[0],rv[1],rv[2],rv[3]);
      else if(resid)
        ld_resid4(resid + (size_t)row0*DMODEL + n, rv[0],rv[1],rv[2],rv[3]);
#pragma unroll
      for(int r=0;r<4;r++){
        int ri = ri0 + r;
        int row = row0 + r;
        float v = acc[rt][ct][r];
        if(bias)  v += bias[n];
        if(ln_mode==2) v += (rv[r] - S.mu[ri])*S.rs[ri]*lng[n] + lnbta[n];
        else if(resid) v += rv[r];
        if(act==1) v = gelu_t(v);
        if(c_mode==0)      st_f1(Cf + (size_t)row*c_rs + n, v);
        else if(c_mode==1) st_b16(Cb + (size_t)row*c_rs + n, f2b(v));
        else {
          int which = n>>9, rem = n&511;
          int b = row>>7, t = row&127;
          st_f1(Cf + (size_t)which*(MROWS*DMODEL) +
                ((size_t)(b*NHEAD + (rem>>6))*SEQ + t)*DHEAD + (rem&63), v);
        }
      }
    }
  }
}

// fused attention per (b,h); 32 rows per body call; writes bf16.
__device__ __forceinline__ void attn_body(int bx, int h, int b, SmemA& S,
                                          const float* __restrict__ qb,
                                          const float* __restrict__ kb,
                                          const float* __restrict__ vbuf,
                                          unsigned short* __restrict__ attb){
  int r0 = bx*32;
  const float* Kh = kb   + (size_t)(b*NHEAD+h)*SEQ*DHEAD;
  const float* Vh = vbuf + (size_t)(b*NHEAD+h)*SEQ*DHEAD;
  const float* Qh = qb   + (size_t)(b*NHEAD+h)*SEQ*DHEAD;
  int tid = threadIdx.x;
  int kk = tid>>4, d4 = (tid&15)*4;

  { // K stage (xor-swizzled) + Q stage, MALL-direct float4 loads, batched
    const float* kp = Kh + kk*DHEAD + d4;
    f32x4 v0,v1,v2,v3;
    ld_f4g4(kp, kp+1024, kp+2048, kp+3072, v0,v1,v2,v3);
    *(f32x4*)&S.kv[kk    ][d4 ^ ( kk     &60)] = v0;
    *(f32x4*)&S.kv[kk+16 ][d4 ^ ((kk+16) &60)] = v1;
    *(f32x4*)&S.kv[kk+32 ][d4 ^ ((kk+32) &60)] = v2;
    *(f32x4*)&S.kv[kk+48 ][d4 ^ ((kk+48) &60)] = v3;
    ld_f4g4(kp+4096, kp+5120, kp+6144, kp+7168, v0,v1,v2,v3);
    *(f32x4*)&S.kv[kk+64 ][d4 ^ ((kk+64) &60)] = v0;
    *(f32x4*)&S.kv[kk+80 ][d4 ^ ((kk+80) &60)] = v1;
    *(f32x4*)&S.kv[kk+96 ][d4 ^ ((kk+96) &60)] = v2;
    *(f32x4*)&S.kv[kk+112][d4 ^ ((kk+112)&60)] = v3;
    const float* qp = Qh + (size_t)(r0+kk)*DHEAD + d4;
    f32x4 q0,q1;
    ld_f4g2(qp, qp+1024, q0, q1);
    *(f32x4*)&S.qs[kk   ][d4] = q0;
    *(f32x4*)&S.qs[kk+16][d4] = q1;
  }
  __syncthreads();

  { // logits: 2 rows x 8 keys per thread, float4 LDS reads
    int rp = tid>>4;
    int kg = tid&15;
    float acc[2][8];
#pragma unroll
    for(int i=0;i<2;i++)
#pragma unroll
      for(int kkk=0;kkk<8;kkk++) acc[i][kkk]=0.f;
#pragma unroll 4
    for(int dd=0;dd<16;dd++){
      float4 q0 = *(const float4*)&S.qs[2*rp][dd*4];
      float4 q1 = *(const float4*)&S.qs[2*rp+1][dd*4];
#pragma unroll
      for(int kkk=0;kkk<8;kkk++){
        int k = 8*kg + kkk;
        int off = (dd*4) ^ (k&60);
        float4 kv4 = *(const float4*)&S.kv[k][off];
        acc[0][kkk] += q0.x*kv4.x + q0.y*kv4.y + q0.z*kv4.z + q0.w*kv4.w;
        acc[1][kkk] += q1.x*kv4.x + q1.y*kv4.y + q1.z*kv4.z + q1.w*kv4.w;
      }
    }
#pragma unroll
    for(int i=0;i<2;i++){
      int t = r0 + 2*rp + i;
#pragma unroll
      for(int kkk=0;kkk<8;kkk++){
        int k = 8*kg + kkk;
        S.wsm[2*rp+i][k] = (k > t) ? acc[i][kkk]*0.125f : NEGF;
      }
    }
  }
  __syncthreads();

  { // softmax per row (all-masked row -> uniform 1/128, faithful to jnp)
    int l2 = tid&63, wv = tid>>6;
    for(int r=wv;r<32;r+=4){
      float l0 = S.wsm[r][l2], l1 = S.wsm[r][l2+64];
      float m = fmaxf(l0,l1);
#pragma unroll
      for(int off=32;off;off>>=1) m = fmaxf(m, __shfl_xor(m,off,64));
      float e0 = expf(l0-m), e1 = expf(l1-m);
      float s = e0+e1;
      s = wave_sum(s);
      float inv = 1.f/s;
      S.wsm[r][l2] = e0*inv; S.wsm[r][l2+64] = e1*inv;
    }
  }
  __syncthreads();

  { // V stage (overwrite kv, no swizzle)
    const float* vp = Vh + kk*DHEAD + d4;
    f32x4 v0,v1,v2,v3;
    ld_f4g4(vp, vp+1024, vp+2048, vp+3072, v0,v1,v2,v3);
    *(f32x4*)&S.kv[kk   ][d4] = v0;
    *(f32x4*)&S.kv[kk+16][d4] = v1;
    *(f32x4*)&S.kv[kk+32][d4] = v2;
    *(f32x4*)&S.kv[kk+48][d4] = v3;
    ld_f4g4(vp+4096, vp+5120, vp+6144, vp+7168, v0,v1,v2,v3);
    *(f32x4*)&S.kv[kk+64 ][d4] = v0;
    *(f32x4*)&S.kv[kk+80 ][d4] = v1;
    *(f32x4*)&S.kv[kk+96 ][d4] = v2;
    *(f32x4*)&S.kv[kk+112][d4] = v3;
  }
  __syncthreads();

  { // out = w @ V, pack bf16, 8B MALL-direct store
    int dq = (tid&15)*4, rg = tid>>4;
    for(int r=rg;r<32;r+=16){
      float4 acc2 = make_float4(0.f,0.f,0.f,0.f);
      for(int k=0;k<SEQ;k++){
        float w0 = S.wsm[r][k];
        float4 v = *(const float4*)&S.kv[k][dq];
        acc2.x += w0*v.x; acc2.y += w0*v.y; acc2.z += w0*v.z; acc2.w += w0*v.w;
      }
      int row = b*SEQ + r0 + r;
      unsigned short* op = attb + (size_t)row*DMODEL + h*DHEAD + dq;
      unsigned short u0=f2b(acc2.x), u1=f2b(acc2.y), u2=f2b(acc2.z), u3=f2b(acc2.w);
      u32x2 pk;
      pk[0] = (unsigned)u0 | ((unsigned)u1<<16);
      pk[1] = (unsigned)u2 | ((unsigned)u3<<16);
      st_u64(op, pk);
    }
  }
}

// ctx = LN2_3(r2[ptr-1]); ctxt = Wr1b@ctx + cb1
__device__ __forceinline__ void ctx_body(int jx, int b, SmemC& S,
                                         const float* __restrict__ r2,
                                         const float* __restrict__ g2,
                                         const float* __restrict__ b2,
                                         const float* __restrict__ Wr1,
                                         const float* __restrict__ cb1,
                                         float* __restrict__ ctxt, int ptr){
  int j0 = jx*128;
  int tid = threadIdx.x;
  const float* rp = r2 + (size_t)(b*SEQ + ptr-1)*DMODEL;
  { // MALL-direct row read: 2 scalars per thread, batched
    float a, bb;
    asm volatile("global_load_dword %0, %2, off sc0 sc1\n\t"
                 "global_load_dword %1, %2, off offset:1024 sc0 sc1\n\t"
                 "s_waitcnt vmcnt(0)"
                 : "=&v"(a), "=&v"(bb) : "v"(rp+tid) : "memory");
    S.raw[tid] = a; S.raw[tid+256] = bb;
  }
  __syncthreads();
  float s = 0.f;
  for(int k=tid;k<DMODEL;k+=256) s += S.raw[k];
  s = blk_sum(s, S.scr);
  float mu = s/(float)DMODEL;
  float v = 0.f;
  for(int k=tid;k<DMODEL;k+=256){ float d0 = S.raw[k]-mu; v += d0*d0; }
  v = blk_sum(v, S.scr);
  float rs = rsqrtf(v/(float)DMODEL + LN_EPS);
  for(int k=tid;k<DMODEL;k+=256) S.ctx[k] = (S.raw[k]-mu)*rs*g2[k] + b2[k];
  __syncthreads();
  int wv = tid>>6, l2 = tid&63;
  for(int jj=wv;jj<128;jj+=4){
    int j = j0+jj;
    const float* wp = Wr1 + (size_t)j*1024 + 512;
    float acc = 0.f;
#pragma unroll
    for(int q=0;q<8;q++){ int k = l2 + 64*q; acc += wp[k]*S.ctx[k]; }
    acc = wave_sum(acc);
    if(l2==0) st_f1(&ctxt[b*DFFN + j], acc + cb1[j]);
  }
}

// fused refine (5 substeps) + finalize; one body call per batch.
__device__ __forceinline__ void refine_body(int b, SmemR& S,
                                            const float* __restrict__ M1,
                                            const float* __restrict__ ctxt,
                                            const float* __restrict__ Wr2,
                                            const float* __restrict__ br2,
                                            float* __restrict__ cur_x,
                                            const float* __restrict__ W_emb,
                                            const float* __restrict__ b_emb,
                                            float* __restrict__ out,
                                            float* __restrict__ h0,
                                            unsigned short* __restrict__ h0b,
                                            int s, int ptr){
  int tid = threadIdx.x;
  if(tid < DIN) S.cur[tid] = cur_x[b*DIN + tid];
  // preload this thread's 8 ctxt scalars (MALL-direct), reused across all 5 substeps
  float uu[8];
  {
    const float* cp = ctxt + b*DFFN + tid;
    asm volatile(
      "global_load_dword %0, %8, off sc0 sc1\n\t"
      "global_load_dword %1, %8, off offset:1024 sc0 sc1\n\t"
      "global_load_dword %2, %8, off offset:2048 sc0 sc1\n\t"
      "global_load_dword %3, %8, off offset:3072 sc0 sc1\n\t"
      "global_load_dword %4, %9, off sc0 sc1\n\t"
      "global_load_dword %5, %9, off offset:1024 sc0 sc1\n\t"
      "global_load_dword %6, %9, off offset:2048 sc0 sc1\n\t"
      "global_load_dword %7, %9, off offset:3072 sc0 sc1\n\t"
      "s_waitcnt vmcnt(0)"
      : "=&v"(uu[0]),"=&v"(uu[1]),"=&v"(uu[2]),"=&v"(uu[3]),
        "=&v"(uu[4]),"=&v"(uu[5]),"=&v"(uu[6]),"=&v"(uu[7])
      : "v"(cp), "v"(cp+1024) : "memory");
  }
  __syncthreads();
  for(int sub=0; sub<5; sub++){
#pragma unroll
    for(int p8=0; p8<8; p8++){
      int jj = tid + p8*256;
      float u = uu[p8];
      const float* mp = M1 + (size_t)jj*DIN;
#pragma unroll
      for(int p=0;p<8;p++){
        float4 mv = *(const float4*)(mp + 4*p);
        u += mv.x*S.cur[4*p] + mv.y*S.cur[4*p+1] + mv.z*S.cur[4*p+2] + mv.w*S.cur[4*p+3];
      }
      S.gs[jj] = gelu_t(u);
    }
    __syncthreads();
    int w = tid>>6, l = tid&63;
#pragma unroll
    for(int q=0;q<8;q++){
      int i = w*8 + q;
      const float* wr = Wr2 + (size_t)i*DFFN;
      float a = 0.f;
#pragma unroll
      for(int p=0;p<8;p++){
        int j0 = p*256 + l*4;
        float4 wv = *(const float4*)(wr + j0);
        float4 gv = *(const float4*)&S.gs[j0];
        a += wv.x*gv.x + wv.y*gv.y + wv.z*gv.z + wv.w*gv.w;
      }
      a = wave_sum(a);
      if(l==0) S.dscr[i] = a;
    }
    __syncthreads();
    if(tid < DIN) S.cur[tid] += S.dscr[tid] + br2[tid];
    __syncthreads();
  }
  if(tid < DIN){
    out[(b*NSTEP + s)*DIN + tid] = S.cur[tid];
    cur_x[b*DIN + tid] = S.cur[tid];
  }
  __syncthreads();
  for(int d=tid; d<DMODEL; d+=256){
    float s2 = 0.f;
#pragma unroll 8
    for(int i=0;i<DIN;i++) s2 += W_emb[d*DIN+i]*S.cur[i];
    float v = SCALE_EMB*(s2 + b_emb[d]) + pe_val(ptr, d);
    size_t idx = (size_t)(b*SEQ + ptr)*DMODEL + d;
    st_f1(h0 + idx, v);
    st_b16(h0b + idx, f2b(v));
  }
}

// ---------------- megakernel params ----------------
struct MegaP {
  const float *ln1g, *ln1b, *b1, *b2v, *ln2g, *ln2b, *Wr1, *W_emb, *b_emb, *Wr2, *br2;
  float *out;
  float *h0; unsigned short *h0b;
  float *r2, *r1;
  float *qb, *kb, *vb; unsigned short *attb, *fbuf16;
  const unsigned short *Wq16, *Wk16, *Wv16, *Wo16, *W116, *W216;
  float *M1, *cb1, *ctxt, *cur_x;
};

// ---------------- persistent megakernel: 22 barriers/step, no L2 invalidates ----------
__global__ __launch_bounds__(256,1) void mega(MegaP p){
  __shared__ SmemU sm;
  const unsigned vbk = blockIdx.x;
  unsigned ep = 0;
#define GS() do{ ++ep; gsync(ep*NBLK); }while(0)

  for(int s=0;s<NSTEP;s++){
    int ptr = TH_ + s;
    for(int l=0;l<4;l++){
      const float* g2p = p.ln2g + (l-1)*DMODEL;   // only valid when l>0
      const float* b2p = p.ln2b + (l-1)*DMODEL;
      const float* g1p = p.ln1g + l*DMODEL;
      const float* b1p = p.ln1b + l*DMODEL;

      // ---- QKV (A = l==0 ? h0b : LN2(r2) fused); N=1536 scatter -> qb/kb/vb ----
      if(vbk < 96){
        int bx = (int)(vbk%12u), by = (int)(vbk/12u);
        if(l==0)
          gemm_body(bx, by, sm.g, p.h0b, DMODEL,
                    p.Wq16 + (size_t)l*262144, p.Wk16 + (size_t)l*262144, p.Wv16 + (size_t)l*262144,
                    nullptr, nullptr, nullptr, nullptr, nullptr, 0,
                    p.qb, nullptr, 0, 2, 0);
        else
          gemm_body(bx, by, sm.g, nullptr, DMODEL,
                    p.Wq16 + (size_t)l*262144, p.Wk16 + (size_t)l*262144, p.Wv16 + (size_t)l*262144,
                    nullptr, nullptr, p.r2, g2p, b2p, 1,
                    p.qb, nullptr, 0, 2, 0);
      }
      GS();

      // ---- attention (128 blocks) ----
      attn_body((int)(vbk&3u), (int)((vbk>>2)&7u), (int)(vbk>>5), sm.a, p.qb, p.kb, p.vb, p.attb);
      GS();

      // ---- Wo: att@Wo^T + (l==0 ? h0 : LN2(r2)) -> r1 fp32 (32 blocks) ----
      if(vbk < 32){
        int bx = (int)(vbk&3u), by = (int)(vbk>>2);
        if(l==0)
          gemm_body(bx, by, sm.g, p.attb, DMODEL,
                    p.Wo16 + (size_t)l*262144, nullptr, nullptr,
                    nullptr, p.h0, nullptr, nullptr, nullptr, 0,
                    p.r1, nullptr, DMODEL, 0, 0);
        else
          gemm_body(bx, by, sm.g, p.attb, DMODEL,
                    p.Wo16 + (size_t)l*262144, nullptr, nullptr,
                    nullptr, nullptr, p.r2, g2p, b2p, 2,
                    p.r1, nullptr, DMODEL, 0, 0);
      }
      GS();

      // ---- FF1: gelu(LN1(r1)@W1^T + b1) -> fbuf bf16 (128 blocks) ----
      gemm_body((int)(vbk&15u), (int)(vbk>>4), sm.g, nullptr, DMODEL,
                p.W116 + (size_t)l*1048576, nullptr, nullptr,
                p.b1 + l*DFFN, nullptr, p.r1, g1p, b1p, 1,
                nullptr, p.fbuf16, DFFN, 1, 1);
      GS();

      // ---- FF2: fbuf@W2^T + b2 + LN1(r1) -> r2 fp32 (32 blocks) ----
      if(vbk < 32)
        gemm_body((int)(vbk&3u), (int)(vbk>>2), sm.g, p.fbuf16, DFFN,
                  p.W216 + (size_t)l*1048576, nullptr, nullptr,
                  p.b2v + l*DMODEL, nullptr, p.r1, g1p, b1p, 2,
                  p.r2, nullptr, DMODEL, 0, 0);
      GS();
    }

    // ---- ctx (64 blocks) ----
    if(vbk < 64)
      ctx_body((int)(vbk&15u), (int)(vbk>>4), sm.c, p.r2,
               p.ln2g + 3*DMODEL, p.ln2b + 3*DMODEL, p.Wr1, p.cb1, p.ctxt, ptr);
    GS();

    // ---- refine + finalize + write next h0 row (4 blocks) ----
    if(vbk < 4)
      refine_body((int)vbk, sm.r, p.M1, p.ctxt, p.Wr2, p.br2, p.cur_x,
                  p.W_emb, p.b_emb, p.out, p.h0, p.h0b, s, ptr);
    GS();
  }
#undef GS
}

// ---------------- host ----------------
extern "C" void kernel_launch(void* const* d_in, const int* in_sizes, int n_in,
                              void* d_out, int out_size, void* d_ws, size_t ws_size,
                              hipStream_t stream) {
  (void)in_sizes; (void)n_in; (void)out_size; (void)ws_size;
  const float* hist = (const float*)d_in[0];
  const float* W_emb= (const float*)d_in[2];
  const float* b_emb= (const float*)d_in[3];
  const float* Wq   = (const float*)d_in[4];
  const float* Wk   = (const float*)d_in[5];
  const float* Wv   = (const float*)d_in[6];
  const float* Wo   = (const float*)d_in[7];
  const float* ln1g = (const float*)d_in[8];
  const float* ln1b = (const float*)d_in[9];
  const float* W1   = (const float*)d_in[10];
  const float* b1   = (const float*)d_in[11];
  const float* W2   = (const float*)d_in[12];
  const float* b2v  = (const float*)d_in[13];
  const float* ln2g = (const float*)d_in[14];
  const float* ln2b = (const float*)d_in[15];
  const float* Wr1  = (const float*)d_in[16];
  const float* br1  = (const float*)d_in[17];
  const float* Wr2  = (const float*)d_in[18];
  const float* br2  = (const float*)d_in[19];
  float* out = (float*)d_out;
  float* ws  = (float*)d_ws;

  const size_t BTD = (size_t)MROWS*DMODEL;      // 262144 floats
  const size_t BTDH = BTD/2;                    // bf16 buffer in float units
  float* h0   = ws;
  unsigned short* h0b = (unsigned short*)(h0 + BTD);
  float* r2   = h0 + BTD + BTDH;
  float* hln  = r2 + BTD;                       // dead (layout compat)
  float* hp   = hln + BTD;                      // reused as r1
  float* qb   = hp + BTD + BTDH;
  float* kb   = qb + BTD;
  float* vb   = kb + BTD;
  unsigned short* attb = (unsigned short*)(vb + BTD);
  unsigned short* fbuf16 = (unsigned short*)qb;   // [512][2048] bf16 (over qb/kb, dead then)
  unsigned short* W16 = (unsigned short*)(qb + 4*BTD);
  float* after_w = qb + 4*BTD + 6291456;
  float* M1   = after_w;
  float* cb1  = M1 + (size_t)DFFN*DIN;
  float* ctxt = cb1 + DFFN;
  float* cur_x= ctxt + NB*DFFN;

  unsigned short* Wq16 = W16;
  unsigned short* Wk16 = W16 + 1048576;
  unsigned short* Wv16 = W16 + 2097152;
  unsigned short* Wo16 = W16 + 3145728;
  unsigned short* W116 = W16 + 4194304;
  unsigned short* W216 = W16 + 8388608;

  conv_w<<<dim3(6144),dim3(256),0,stream>>>(Wq,Wk,Wv,Wo,W1,W2,W16);
  init_h0<<<dim3(MROWS),dim3(256),0,stream>>>(hist,W_emb,b_emb,h0,h0b);
  init_misc<<<dim3(256),dim3(256),0,stream>>>(Wr1,W_emb,b_emb,br1,hist,M1,cb1,cur_x);

  MegaP p;
  p.ln1g=ln1g; p.ln1b=ln1b; p.b1=b1; p.b2v=b2v; p.ln2g=ln2g; p.ln2b=ln2b;
  p.Wr1=Wr1; p.W_emb=W_emb; p.b_emb=b_emb; p.Wr2=Wr2; p.br2=br2;
  p.out=out;
  p.h0=h0; p.h0b=h0b;
  p.r2=r2; p.r1=hp;
  p.qb=qb; p.kb=kb; p.vb=vb; p.attb=attb; p.fbuf16=fbuf16;
  p.Wq16=Wq16; p.Wk16=Wk16; p.Wv16=Wv16; p.Wo16=Wo16; p.W116=W116; p.W216=W216;
  p.M1=M1; p.cb1=cb1; p.ctxt=ctxt; p.cur_x=cur_x;

  mega<<<dim3(NBLK),dim3(256),0,stream>>>(p);
}

// Round 4
// 8094.847 us; speedup vs baseline: 1.0347x; 1.0347x over previous
//
#include <hip/hip_runtime.h>
#include <math.h>

// ---------------- problem constants ----------------
namespace {
constexpr int NB = 4;
constexpr int SEQ = 128;
constexpr int TH_ = 120;
constexpr int NSTEP = 8;
constexpr int DMODEL = 512;
constexpr int NHEAD = 8;
constexpr int DHEAD = 64;
constexpr int DFFN = 2048;
constexpr int DIN = 32;
constexpr int MROWS = NB*SEQ;   // 512 flattened rows
constexpr float SCALE_EMB = 22.627416997969522f; // sqrt(512)
constexpr float LN_EPS = 1e-5f;
constexpr float NEGF = -3.4028234663852886e38f;  // jnp.finfo(f32).min
constexpr float PE_C = -0.017988946039015984f;   // -ln(10000)/512
constexpr unsigned NBLK = 128;  // persistent grid: 128 blocks < 256 CUs -> co-resident
constexpr int FL_STRIDE = 32;   // dwords between flag slots (128 B, one line each)
}

using short8 = __attribute__((ext_vector_type(8))) short;
using f32x4  = __attribute__((ext_vector_type(4))) float;
using u32x2  = __attribute__((ext_vector_type(2))) unsigned int;

// ---------------- device helpers ----------------
__device__ __forceinline__ float wave_sum(float v){
#pragma unroll
  for(int off=32;off;off>>=1) v += __shfl_xor(v,off,64);
  return v;
}
__device__ __forceinline__ float blk_sum(float v, float* scr){
  v = wave_sum(v);
  __syncthreads();
  if((threadIdx.x&63)==0) scr[threadIdx.x>>6]=v;
  __syncthreads();
  return scr[0]+scr[1]+scr[2]+scr[3];
}
__device__ __forceinline__ float gelu_t(float x){
  float t = 0.7978845608028654f*(x + 0.044715f*x*x*x);
  return 0.5f*x*(1.0f + tanhf(t));
}
__device__ __forceinline__ float pe_val(int t, int d){
  float div = expf((float)(d & ~1) * PE_C);
  float a = (float)t * div;
  return (d & 1) ? cosf(a) : sinf(a);
}
__device__ __forceinline__ unsigned short f2b(float f){
  union { float f; unsigned u; } c; c.f = f;
  unsigned u = c.u + 0x7FFFu + ((c.u>>16)&1u);
  return (unsigned short)(u>>16);
}
__device__ __forceinline__ short8 pack8(const float* f){
  short8 s;
#pragma unroll
  for(int i=0;i<8;i++) s[i] = (short)f2b(f[i]);
  return s;
}

// ---------------- MALL-direct (cross-XCD coherent, L2-bypass) access helpers -----------
__device__ __forceinline__ void ld_a32(const unsigned short* p, short8& a0, short8& a1){
  asm volatile("global_load_dwordx4 %0, %2, off sc0 sc1\n\t"
               "global_load_dwordx4 %1, %2, off offset:16 sc0 sc1\n\t"
               "s_waitcnt vmcnt(0)"
               : "=&v"(a0), "=&v"(a1) : "v"(p) : "memory");
}
__device__ __forceinline__ void ld_f4x4(const float* p, f32x4& a, f32x4& b, f32x4& c, f32x4& d){
  asm volatile("global_load_dwordx4 %0, %4, off sc0 sc1\n\t"
               "global_load_dwordx4 %1, %4, off offset:16 sc0 sc1\n\t"
               "global_load_dwordx4 %2, %4, off offset:32 sc0 sc1\n\t"
               "global_load_dwordx4 %3, %4, off offset:48 sc0 sc1\n\t"
               "s_waitcnt vmcnt(0)"
               : "=&v"(a),"=&v"(b),"=&v"(c),"=&v"(d) : "v"(p) : "memory");
}
__device__ __forceinline__ void ld_f4x8(const float* p0,const float* p1,const float* p2,const float* p3,
                                        f32x4& a0, f32x4& a1, f32x4& b0, f32x4& b1,
                                        f32x4& c0, f32x4& c1, f32x4& d0, f32x4& d1){
  asm volatile(
    "global_load_dwordx4 %0, %8, off sc0 sc1\n\t"
    "global_load_dwordx4 %1, %8, off offset:16 sc0 sc1\n\t"
    "global_load_dwordx4 %2, %9, off sc0 sc1\n\t"
    "global_load_dwordx4 %3, %9, off offset:16 sc0 sc1\n\t"
    "global_load_dwordx4 %4, %10, off sc0 sc1\n\t"
    "global_load_dwordx4 %5, %10, off offset:16 sc0 sc1\n\t"
    "global_load_dwordx4 %6, %11, off sc0 sc1\n\t"
    "global_load_dwordx4 %7, %11, off offset:16 sc0 sc1\n\t"
    "s_waitcnt vmcnt(0)"
    : "=&v"(a0),"=&v"(a1),"=&v"(b0),"=&v"(b1),"=&v"(c0),"=&v"(c1),"=&v"(d0),"=&v"(d1)
    : "v"(p0),"v"(p1),"v"(p2),"v"(p3) : "memory");
}
__device__ __forceinline__ void ld_f4g4(const float* p0,const float* p1,const float* p2,const float* p3,
                                        f32x4& a, f32x4& b, f32x4& c, f32x4& d){
  asm volatile(
    "global_load_dwordx4 %0, %4, off sc0 sc1\n\t"
    "global_load_dwordx4 %1, %5, off sc0 sc1\n\t"
    "global_load_dwordx4 %2, %6, off sc0 sc1\n\t"
    "global_load_dwordx4 %3, %7, off sc0 sc1\n\t"
    "s_waitcnt vmcnt(0)"
    : "=&v"(a),"=&v"(b),"=&v"(c),"=&v"(d)
    : "v"(p0),"v"(p1),"v"(p2),"v"(p3) : "memory");
}
__device__ __forceinline__ void ld_f4g2(const float* p0,const float* p1, f32x4& a, f32x4& b){
  asm volatile(
    "global_load_dwordx4 %0, %2, off sc0 sc1\n\t"
    "global_load_dwordx4 %1, %3, off sc0 sc1\n\t"
    "s_waitcnt vmcnt(0)"
    : "=&v"(a),"=&v"(b) : "v"(p0),"v"(p1) : "memory");
}
// 4 scalar loads at row-stride DMODEL (2048B): rows r..r+3 of column n
__device__ __forceinline__ void ld_resid4(const float* p, float& a,float& b,float& c,float& d){
  asm volatile(
    "global_load_dword %0, %4, off sc0 sc1\n\t"
    "global_load_dword %1, %4, off offset:2048 sc0 sc1\n\t"
    "global_load_dword %2, %5, off sc0 sc1\n\t"
    "global_load_dword %3, %5, off offset:2048 sc0 sc1\n\t"
    "s_waitcnt vmcnt(0)"
    : "=&v"(a),"=&v"(b),"=&v"(c),"=&v"(d)
    : "v"(p), "v"(p+2*DMODEL) : "memory");
}
__device__ __forceinline__ void st_f1(float* p, float v){
  asm volatile("global_store_dword %0, %1, off sc0 sc1" :: "v"(p), "v"(v) : "memory");
}
__device__ __forceinline__ void st_b16(unsigned short* p, unsigned short v){
  unsigned w32 = v;
  asm volatile("global_store_short %0, %1, off sc0 sc1" :: "v"(p), "v"(w32) : "memory");
}
__device__ __forceinline__ void st_u64(void* p, u32x2 v){
  asm volatile("global_store_dwordx2 %0, %1, off sc0 sc1" :: "v"(p), "v"(v) : "memory");
}
__device__ __forceinline__ void st_u32_wt(unsigned* p, unsigned v){
  asm volatile("global_store_dword %0, %1, off sc0 sc1" :: "v"(p), "v"(v) : "memory");
}

// ---------------- all-to-all flag barrier: NO atomic RMW, NO shared hot line ----------
// Arrive: (per-thread) vmcnt(0) drains own data stores to the coherence point;
//         block-barrier; thread 0 stores epoch to the block's OWN 128B-spaced slot.
// Wait:   threads 0..127 each poll ONE flag with an sc0sc1 bypass load.
// flag[j] >= ep  =>  block j's data stores are globally visible (store-ack ordering).
__device__ __forceinline__ void gsync(unsigned* FL, unsigned ep, unsigned vbk){
  asm volatile("s_waitcnt vmcnt(0)" ::: "memory");
  __syncthreads();
  int tid = threadIdx.x;
  if(tid==0){
    unsigned* mp = FL + (size_t)vbk*FL_STRIDE;
    asm volatile("global_store_dword %0, %1, off sc0 sc1\n\t"
                 "s_waitcnt vmcnt(0)" :: "v"(mp), "v"(ep) : "memory");
  }
  if(tid < (int)NBLK){
    const unsigned* p = FL + (size_t)tid*FL_STRIDE;
    unsigned v;
    for(;;){
      asm volatile("global_load_dword %0, %1, off sc0 sc1\n\t"
                   "s_waitcnt vmcnt(0)" : "=v"(v) : "v"(p) : "memory");
      if(v >= ep) break;
      __builtin_amdgcn_s_sleep(1);
    }
  }
  __syncthreads();
}

// ---------------- shared-memory union (one allocation reused by every stage) ----------
struct SmemG { unsigned short As[64][72]; unsigned short Bs[128][72];
               float mu[64]; float rs[64]; };                                     // 28.2 KB
struct SmemA { float kv[SEQ][DHEAD]; float wsm[32][132]; float qs[32][68]; };     // 58.4 KB
struct SmemC { float raw[DMODEL]; float ctx[DMODEL]; float scr[4]; };             //  4.1 KB
struct SmemR { float cur[DIN]; float gs[DFFN]; float dscr[DIN]; };                //  8.4 KB
union alignas(16) SmemU { SmemG g; SmemA a; SmemC c; SmemR r; };

// ---------------- one-time: convert all weights to bf16 ----------------
__global__ __launch_bounds__(256) void conv_w(const float* __restrict__ Wq,
                                              const float* __restrict__ Wk,
                                              const float* __restrict__ Wv,
                                              const float* __restrict__ Wo,
                                              const float* __restrict__ W1,
                                              const float* __restrict__ W2,
                                              unsigned short* __restrict__ dst){
  size_t base = ((size_t)blockIdx.x*256 + threadIdx.x)*8;
  if(base >= 12582912u) return;
  const float* src; size_t off;
  if(base < 1048576u){ src=Wq; off=base; }
  else if(base < 2097152u){ src=Wk; off=base-1048576u; }
  else if(base < 3145728u){ src=Wv; off=base-2097152u; }
  else if(base < 4194304u){ src=Wo; off=base-3145728u; }
  else if(base < 8388608u){ src=W1; off=base-4194304u; }
  else { src=W2; off=base-8388608u; }
  float4 a = *(const float4*)(src+off);
  float4 b = *(const float4*)(src+off+4);
  float f[8] = {a.x,a.y,a.z,a.w,b.x,b.y,b.z,b.w};
  *(short8*)(dst + base) = pack8(f);
}

// ---------------- h0 init (fp32 + bf16) ----------------
__global__ __launch_bounds__(256) void init_h0(const float* __restrict__ hist,
                                               const float* __restrict__ W_emb,
                                               const float* __restrict__ b_emb,
                                               float* __restrict__ h0,
                                               unsigned short* __restrict__ h0b){
  int bt = blockIdx.x;
  int b = bt >> 7, t = bt & 127;
  __shared__ float x[DIN];
  if(threadIdx.x < DIN)
    x[threadIdx.x] = (t < TH_) ? hist[((size_t)b*TH_ + t)*DIN + threadIdx.x] : 0.f;
  __syncthreads();
  for(int d = threadIdx.x; d < DMODEL; d += 256){
    float s = 0.f;
#pragma unroll 8
    for(int i=0;i<DIN;i++) s += W_emb[d*DIN+i]*x[i];
    float v = SCALE_EMB*(s + b_emb[d]) + pe_val(t,d);
    h0[(size_t)bt*DMODEL + d] = v;
    h0b[(size_t)bt*DMODEL + d] = f2b(v);
  }
}

// ---------------- M1 / cb1 / cur_x init (+ flag zeroing, write-through) ----------------
__global__ __launch_bounds__(256) void init_misc(const float* __restrict__ Wr1,
                                                 const float* __restrict__ W_emb,
                                                 const float* __restrict__ b_emb,
                                                 const float* __restrict__ br1,
                                                 const float* __restrict__ hist,
                                                 float* __restrict__ M1,
                                                 float* __restrict__ cb1,
                                                 float* __restrict__ cur_x,
                                                 unsigned* __restrict__ FL){
  if(blockIdx.x < 16){   // zero all 128 flag slots (4096 dwords), write-through
    unsigned idx = blockIdx.x*256u + threadIdx.x;
    st_u32_wt(FL + idx, 0u);
  }
  __shared__ float row[DMODEL];
  int j0 = blockIdx.x*8;
  for(int jj=0;jj<8;jj++){
    int j = j0+jj;
    for(int k=threadIdx.x;k<DMODEL;k+=256) row[k] = Wr1[(size_t)j*1024 + k];
    __syncthreads();
    if(threadIdx.x < DIN){
      int i = threadIdx.x; float s = 0.f;
      for(int k=0;k<DMODEL;k++) s += row[k]*W_emb[k*DIN+i];
      M1[j*DIN+i] = SCALE_EMB*s;
    } else if(threadIdx.x == DIN){
      float s=0.f;
      for(int k=0;k<DMODEL;k++) s += row[k]*b_emb[k];
      cb1[j] = br1[j] + SCALE_EMB*s;
    }
    __syncthreads();
  }
  if(blockIdx.x==0 && threadIdx.x<NB*DIN){
    int b = threadIdx.x>>5, i = threadIdx.x&31;
    cur_x[b*DIN+i] = hist[((size_t)b*TH_ + (TH_-1))*DIN + i];
  }
}

// ---------------- bf16 MFMA GEMM tile 64x128, 4 waves, with optional fused LN ----------
// ln_mode: 0 = none; 1 = A operand is LN(lnx)*g+b packed bf16 on the fly;
//          2 = epilogue residual is LN(lnx)*g+b.
// Activation traffic (A16 / lnx / resid / C outputs) is MALL-direct; weights cached.
__device__ __forceinline__ void gemm_body(int bx, int by, SmemG& S,
    const unsigned short* __restrict__ A16, int Ka,
    const unsigned short* __restrict__ Wa,
    const unsigned short* __restrict__ Wb,
    const unsigned short* __restrict__ Wc,
    const float* __restrict__ bias, const float* __restrict__ resid,
    const float* __restrict__ lnx, const float* __restrict__ lng,
    const float* __restrict__ lnbta, int ln_mode,
    float* __restrict__ Cf, unsigned short* __restrict__ Cb,
    int c_rs, int c_mode, int act)
{
  int n0 = bx*128;
  int m0 = by*64;
  int tid = threadIdx.x, w = tid>>6, ln = tid&63;

  const unsigned short* Wsrc; int nrow0;
  if(c_mode==2){ int which = n0>>9; Wsrc = (which==0?Wa:(which==1?Wb:Wc)); nrow0 = n0&511; }
  else { Wsrc = Wa; nrow0 = n0; }

  // ---- LN row-stats prologue (exact wave-per-row reduction -> bit-identical mu/rs) ----
  if(ln_mode){
    int l = tid&63;
    for(int rr=0;rr<16;rr+=4){
      int rw = w*16 + rr;
      const float* xp = lnx + (size_t)(m0+rw)*DMODEL + l*8;
      f32x4 xa0,xa1,xb0,xb1,xc0,xc1,xd0,xd1;
      ld_f4x8(xp, xp+DMODEL, xp+2*DMODEL, xp+3*DMODEL,
              xa0,xa1,xb0,xb1,xc0,xc1,xd0,xd1);
      f32x4 lo[4] = {xa0,xb0,xc0,xd0};
      f32x4 hi[4] = {xa1,xb1,xc1,xd1};
#pragma unroll
      for(int j=0;j<4;j++){
        float f[8];
#pragma unroll
        for(int i=0;i<4;i++){ f[i]=lo[j][i]; f[4+i]=hi[j][i]; }
        float s = 0.f;
#pragma unroll
        for(int i=0;i<8;i++) s += f[i];
        s = wave_sum(s);
        float mu = s*(1.f/DMODEL);
        float v2 = 0.f;
#pragma unroll
        for(int i=0;i<8;i++){ float d0=f[i]-mu; v2 += d0*d0; }
        v2 = wave_sum(v2);
        float rsv = rsqrtf(v2*(1.f/DMODEL) + LN_EPS);
        if(l==0){ S.mu[rw+j]=mu; S.rs[rw+j]=rsv; }
      }
    }
    __syncthreads();
  }

  f32x4 acc[4][2];
#pragma unroll
  for(int i=0;i<4;i++)
#pragma unroll
    for(int j=0;j<2;j++) acc[i][j] = (f32x4){0.f,0.f,0.f,0.f};

  int fr = ln&15, fq = (ln>>4)*8;
  int arow = tid>>2, akq = (tid&3)*16;
  int brow = tid>>1, bkq = (tid&1)*32;

  float amu=0.f, ars=0.f;
  if(ln_mode==1){ amu = S.mu[arow]; ars = S.rs[arow]; }

  for(int k0=0;k0<Ka;k0+=64){
    // B first: plain cached loads (weights, L2-hot)
    const unsigned short* bp = Wsrc + (size_t)(nrow0+brow)*Ka + k0 + bkq;
    short8 b0 = *(const short8*)bp;
    short8 b1 = *(const short8*)(bp+8);
    short8 b2 = *(const short8*)(bp+16);
    short8 b3 = *(const short8*)(bp+24);
    if(ln_mode==1){
      const float* fp = lnx + (size_t)(m0+arow)*DMODEL + k0 + akq;
      f32x4 t0,t1,t2,t3;
      ld_f4x4(fp, t0,t1,t2,t3);
      const float* gp = lng + k0 + akq;
      const float* cp = lnbta + k0 + akq;
      float4 g0 = *(const float4*)(gp);
      float4 g1 = *(const float4*)(gp+4);
      float4 g2 = *(const float4*)(gp+8);
      float4 g3 = *(const float4*)(gp+12);
      float4 c0 = *(const float4*)(cp);
      float4 c1 = *(const float4*)(cp+4);
      float4 c2 = *(const float4*)(cp+8);
      float4 c3 = *(const float4*)(cp+12);
      float tt[16], gg[16], cc[16];
#pragma unroll
      for(int i=0;i<4;i++){ tt[i]=t0[i]; tt[4+i]=t1[i]; tt[8+i]=t2[i]; tt[12+i]=t3[i]; }
      gg[0]=g0.x; gg[1]=g0.y; gg[2]=g0.z; gg[3]=g0.w;
      gg[4]=g1.x; gg[5]=g1.y; gg[6]=g1.z; gg[7]=g1.w;
      gg[8]=g2.x; gg[9]=g2.y; gg[10]=g2.z; gg[11]=g2.w;
      gg[12]=g3.x; gg[13]=g3.y; gg[14]=g3.z; gg[15]=g3.w;
      cc[0]=c0.x; cc[1]=c0.y; cc[2]=c0.z; cc[3]=c0.w;
      cc[4]=c1.x; cc[5]=c1.y; cc[6]=c1.z; cc[7]=c1.w;
      cc[8]=c2.x; cc[9]=c2.y; cc[10]=c2.z; cc[11]=c2.w;
      cc[12]=c3.x; cc[13]=c3.y; cc[14]=c3.z; cc[15]=c3.w;
      float o[16];
#pragma unroll
      for(int i=0;i<16;i++) o[i] = (tt[i]-amu)*ars*gg[i] + cc[i];
      *(short8*)&S.As[arow][akq]   = pack8(o);
      *(short8*)&S.As[arow][akq+8] = pack8(o+8);
    } else {
      short8 a0, a1;
      ld_a32(A16 + (size_t)(m0+arow)*Ka + k0 + akq, a0, a1);
      *(short8*)&S.As[arow][akq]   = a0;
      *(short8*)&S.As[arow][akq+8] = a1;
    }
    *(short8*)&S.Bs[brow][bkq]    = b0;
    *(short8*)&S.Bs[brow][bkq+8]  = b1;
    *(short8*)&S.Bs[brow][bkq+16] = b2;
    *(short8*)&S.Bs[brow][bkq+24] = b3;
    __syncthreads();
    short8 af[4][2], bf[2][2];
#pragma unroll
    for(int kf=0;kf<2;kf++){
#pragma unroll
      for(int rt=0;rt<4;rt++) af[rt][kf] = *(const short8*)&S.As[rt*16 + fr][kf*32 + fq];
#pragma unroll
      for(int ct=0;ct<2;ct++) bf[ct][kf] = *(const short8*)&S.Bs[32*w + ct*16 + fr][kf*32 + fq];
    }
#pragma unroll
    for(int kf=0;kf<2;kf++)
#pragma unroll
      for(int rt=0;rt<4;rt++)
#pragma unroll
        for(int ct=0;ct<2;ct++)
          acc[rt][ct] = __builtin_amdgcn_mfma_f32_16x16x32_bf16(af[rt][kf], bf[ct][kf], acc[rt][ct], 0, 0, 0);
    __syncthreads();
  }

#pragma unroll
  for(int rt=0;rt<4;rt++){
#pragma unroll
    for(int ct=0;ct<2;ct++){
      int n = n0 + 32*w + ct*16 + fr;
      int ri0 = rt*16 + (ln>>4)*4;
      int row0 = m0 + ri0;
      float rv[4] = {0.f,0.f,0.f,0.f};
      if(ln_mode==2)
        ld_resid4(lnx + (size_t)row0*DMODEL + n, rv[0],rv[1],rv[2],rv[3]);
      else if(resid)
        ld_resid4(resid + (size_t)row0*DMODEL + n, rv[0],rv[1],rv[2],rv[3]);
#pragma unroll
      for(int r=0;r<4;r++){
        int ri = ri0 + r;
        int row = row0 + r;
        float v = acc[rt][ct][r];
        if(bias)  v += bias[n];
        if(ln_mode==2) v += (rv[r] - S.mu[ri])*S.rs[ri]*lng[n] + lnbta[n];
        else if(resid) v += rv[r];
        if(act==1) v = gelu_t(v);
        if(c_mode==0)      st_f1(Cf + (size_t)row*c_rs + n, v);
        else if(c_mode==1) st_b16(Cb + (size_t)row*c_rs + n, f2b(v));
        else {
          int which = n>>9, rem = n&511;
          int b = row>>7, t = row&127;
          st_f1(Cf + (size_t)which*(MROWS*DMODEL) +
                ((size_t)(b*NHEAD + (rem>>6))*SEQ + t)*DHEAD + (rem&63), v);
        }
      }
    }
  }
}

// fused attention per (b,h); 32 rows per body call; writes bf16.
__device__ __forceinline__ void attn_body(int bx, int h, int b, SmemA& S,
                                          const float* __restrict__ qb,
                                          const float* __restrict__ kb,
                                          const float* __restrict__ vbuf,
                                          unsigned short* __restrict__ attb){
  int r0 = bx*32;
  const float* Kh = kb   + (size_t)(b*NHEAD+h)*SEQ*DHEAD;
  const float* Vh = vbuf + (size_t)(b*NHEAD+h)*SEQ*DHEAD;
  const float* Qh = qb   + (size_t)(b*NHEAD+h)*SEQ*DHEAD;
  int tid = threadIdx.x;
  int kk = tid>>4, d4 = (tid&15)*4;

  { // K stage (xor-swizzled) + Q stage, MALL-direct float4 loads, batched
    const float* kp = Kh + kk*DHEAD + d4;
    f32x4 v0,v1,v2,v3;
    ld_f4g4(kp, kp+1024, kp+2048, kp+3072, v0,v1,v2,v3);
    *(f32x4*)&S.kv[kk    ][d4 ^ ( kk     &60)] = v0;
    *(f32x4*)&S.kv[kk+16 ][d4 ^ ((kk+16) &60)] = v1;
    *(f32x4*)&S.kv[kk+32 ][d4 ^ ((kk+32) &60)] = v2;
    *(f32x4*)&S.kv[kk+48 ][d4 ^ ((kk+48) &60)] = v3;
    ld_f4g4(kp+4096, kp+5120, kp+6144, kp+7168, v0,v1,v2,v3);
    *(f32x4*)&S.kv[kk+64 ][d4 ^ ((kk+64) &60)] = v0;
    *(f32x4*)&S.kv[kk+80 ][d4 ^ ((kk+80) &60)] = v1;
    *(f32x4*)&S.kv[kk+96 ][d4 ^ ((kk+96) &60)] = v2;
    *(f32x4*)&S.kv[kk+112][d4 ^ ((kk+112)&60)] = v3;
    const float* qp = Qh + (size_t)(r0+kk)*DHEAD + d4;
    f32x4 q0,q1;
    ld_f4g2(qp, qp+1024, q0, q1);
    *(f32x4*)&S.qs[kk   ][d4] = q0;
    *(f32x4*)&S.qs[kk+16][d4] = q1;
  }
  __syncthreads();

  { // logits: 2 rows x 8 keys per thread, float4 LDS reads
    int rp = tid>>4;
    int kg = tid&15;
    float acc[2][8];
#pragma unroll
    for(int i=0;i<2;i++)
#pragma unroll
      for(int kkk=0;kkk<8;kkk++) acc[i][kkk]=0.f;
#pragma unroll 4
    for(int dd=0;dd<16;dd++){
      float4 q0 = *(const float4*)&S.qs[2*rp][dd*4];
      float4 q1 = *(const float4*)&S.qs[2*rp+1][dd*4];
#pragma unroll
      for(int kkk=0;kkk<8;kkk++){
        int k = 8*kg + kkk;
        int off = (dd*4) ^ (k&60);
        float4 kv4 = *(const float4*)&S.kv[k][off];
        acc[0][kkk] += q0.x*kv4.x + q0.y*kv4.y + q0.z*kv4.z + q0.w*kv4.w;
        acc[1][kkk] += q1.x*kv4.x + q1.y*kv4.y + q1.z*kv4.z + q1.w*kv4.w;
      }
    }
#pragma unroll
    for(int i=0;i<2;i++){
      int t = r0 + 2*rp + i;
#pragma unroll
      for(int kkk=0;kkk<8;kkk++){
        int k = 8*kg + kkk;
        S.wsm[2*rp+i][k] = (k > t) ? acc[i][kkk]*0.125f : NEGF;
      }
    }
  }
  __syncthreads();

  { // softmax per row (all-masked row -> uniform 1/128, faithful to jnp)
    int l2 = tid&63, wv = tid>>6;
    for(int r=wv;r<32;r+=4){
      float l0 = S.wsm[r][l2], l1 = S.wsm[r][l2+64];
      float m = fmaxf(l0,l1);
#pragma unroll
      for(int off=32;off;off>>=1) m = fmaxf(m, __shfl_xor(m,off,64));
      float e0 = expf(l0-m), e1 = expf(l1-m);
      float s = e0+e1;
      s = wave_sum(s);
      float inv = 1.f/s;
      S.wsm[r][l2] = e0*inv; S.wsm[r][l2+64] = e1*inv;
    }
  }
  __syncthreads();

  { // V stage (overwrite kv, no swizzle)
    const float* vp = Vh + kk*DHEAD + d4;
    f32x4 v0,v1,v2,v3;
    ld_f4g4(vp, vp+1024, vp+2048, vp+3072, v0,v1,v2,v3);
    *(f32x4*)&S.kv[kk   ][d4] = v0;
    *(f32x4*)&S.kv[kk+16][d4] = v1;
    *(f32x4*)&S.kv[kk+32][d4] = v2;
    *(f32x4*)&S.kv[kk+48][d4] = v3;
    ld_f4g4(vp+4096, vp+5120, vp+6144, vp+7168, v0,v1,v2,v3);
    *(f32x4*)&S.kv[kk+64 ][d4] = v0;
    *(f32x4*)&S.kv[kk+80 ][d4] = v1;
    *(f32x4*)&S.kv[kk+96 ][d4] = v2;
    *(f32x4*)&S.kv[kk+112][d4] = v3;
  }
  __syncthreads();

  { // out = w @ V, pack bf16, 8B MALL-direct store
    int dq = (tid&15)*4, rg = tid>>4;
    for(int r=rg;r<32;r+=16){
      float4 acc2 = make_float4(0.f,0.f,0.f,0.f);
      for(int k=0;k<SEQ;k++){
        float w0 = S.wsm[r][k];
        float4 v = *(const float4*)&S.kv[k][dq];
        acc2.x += w0*v.x; acc2.y += w0*v.y; acc2.z += w0*v.z; acc2.w += w0*v.w;
      }
      int row = b*SEQ + r0 + r;
      unsigned short* op = attb + (size_t)row*DMODEL + h*DHEAD + dq;
      unsigned short u0=f2b(acc2.x), u1=f2b(acc2.y), u2=f2b(acc2.z), u3=f2b(acc2.w);
      u32x2 pk;
      pk[0] = (unsigned)u0 | ((unsigned)u1<<16);
      pk[1] = (unsigned)u2 | ((unsigned)u3<<16);
      st_u64(op, pk);
    }
  }
}

// ctx = LN2_3(r2[ptr-1]); ctxt = Wr1b@ctx + cb1
__device__ __forceinline__ void ctx_body(int jx, int b, SmemC& S,
                                         const float* __restrict__ r2,
                                         const float* __restrict__ g2,
                                         const float* __restrict__ b2,
                                         const float* __restrict__ Wr1,
                                         const float* __restrict__ cb1,
                                         float* __restrict__ ctxt, int ptr){
  int j0 = jx*128;
  int tid = threadIdx.x;
  const float* rp = r2 + (size_t)(b*SEQ + ptr-1)*DMODEL;
  { // MALL-direct row read: 2 scalars per thread, batched
    float a, bb;
    asm volatile("global_load_dword %0, %2, off sc0 sc1\n\t"
                 "global_load_dword %1, %2, off offset:1024 sc0 sc1\n\t"
                 "s_waitcnt vmcnt(0)"
                 : "=&v"(a), "=&v"(bb) : "v"(rp+tid) : "memory");
    S.raw[tid] = a; S.raw[tid+256] = bb;
  }
  __syncthreads();
  float s = 0.f;
  for(int k=tid;k<DMODEL;k+=256) s += S.raw[k];
  s = blk_sum(s, S.scr);
  float mu = s/(float)DMODEL;
  float v = 0.f;
  for(int k=tid;k<DMODEL;k+=256){ float d0 = S.raw[k]-mu; v += d0*d0; }
  v = blk_sum(v, S.scr);
  float rs = rsqrtf(v/(float)DMODEL + LN_EPS);
  for(int k=tid;k<DMODEL;k+=256) S.ctx[k] = (S.raw[k]-mu)*rs*g2[k] + b2[k];
  __syncthreads();
  int wv = tid>>6, l2 = tid&63;
  for(int jj=wv;jj<128;jj+=4){
    int j = j0+jj;
    const float* wp = Wr1 + (size_t)j*1024 + 512;
    float acc = 0.f;
#pragma unroll
    for(int q=0;q<8;q++){ int k = l2 + 64*q; acc += wp[k]*S.ctx[k]; }
    acc = wave_sum(acc);
    if(l2==0) st_f1(&ctxt[b*DFFN + j], acc + cb1[j]);
  }
}

// fused refine (5 substeps) + finalize; one body call per batch.
__device__ __forceinline__ void refine_body(int b, SmemR& S,
                                            const float* __restrict__ M1,
                                            const float* __restrict__ ctxt,
                                            const float* __restrict__ Wr2,
                                            const float* __restrict__ br2,
                                            float* __restrict__ cur_x,
                                            const float* __restrict__ W_emb,
                                            const float* __restrict__ b_emb,
                                            float* __restrict__ out,
                                            float* __restrict__ h0,
                                            unsigned short* __restrict__ h0b,
                                            int s, int ptr){
  int tid = threadIdx.x;
  if(tid < DIN) S.cur[tid] = cur_x[b*DIN + tid];
  // preload this thread's 8 ctxt scalars (MALL-direct), reused across all 5 substeps
  float uu[8];
  {
    const float* cp = ctxt + b*DFFN + tid;
    asm volatile(
      "global_load_dword %0, %8, off sc0 sc1\n\t"
      "global_load_dword %1, %8, off offset:1024 sc0 sc1\n\t"
      "global_load_dword %2, %8, off offset:2048 sc0 sc1\n\t"
      "global_load_dword %3, %8, off offset:3072 sc0 sc1\n\t"
      "global_load_dword %4, %9, off sc0 sc1\n\t"
      "global_load_dword %5, %9, off offset:1024 sc0 sc1\n\t"
      "global_load_dword %6, %9, off offset:2048 sc0 sc1\n\t"
      "global_load_dword %7, %9, off offset:3072 sc0 sc1\n\t"
      "s_waitcnt vmcnt(0)"
      : "=&v"(uu[0]),"=&v"(uu[1]),"=&v"(uu[2]),"=&v"(uu[3]),
        "=&v"(uu[4]),"=&v"(uu[5]),"=&v"(uu[6]),"=&v"(uu[7])
      : "v"(cp), "v"(cp+1024) : "memory");
  }
  __syncthreads();
  for(int sub=0; sub<5; sub++){
#pragma unroll
    for(int p8=0; p8<8; p8++){
      int jj = tid + p8*256;
      float u = uu[p8];
      const float* mp = M1 + (size_t)jj*DIN;
#pragma unroll
      for(int p=0;p<8;p++){
        float4 mv = *(const float4*)(mp + 4*p);
        u += mv.x*S.cur[4*p] + mv.y*S.cur[4*p+1] + mv.z*S.cur[4*p+2] + mv.w*S.cur[4*p+3];
      }
      S.gs[jj] = gelu_t(u);
    }
    __syncthreads();
    int w = tid>>6, l = tid&63;
#pragma unroll
    for(int q=0;q<8;q++){
      int i = w*8 + q;
      const float* wr = Wr2 + (size_t)i*DFFN;
      float a = 0.f;
#pragma unroll
      for(int p=0;p<8;p++){
        int j0 = p*256 + l*4;
        float4 wv = *(const float4*)(wr + j0);
        float4 gv = *(const float4*)&S.gs[j0];
        a += wv.x*gv.x + wv.y*gv.y + wv.z*gv.z + wv.w*gv.w;
      }
      a = wave_sum(a);
      if(l==0) S.dscr[i] = a;
    }
    __syncthreads();
    if(tid < DIN) S.cur[tid] += S.dscr[tid] + br2[tid];
    __syncthreads();
  }
  if(tid < DIN){
    out[(b*NSTEP + s)*DIN + tid] = S.cur[tid];
    cur_x[b*DIN + tid] = S.cur[tid];
  }
  __syncthreads();
  for(int d=tid; d<DMODEL; d+=256){
    float s2 = 0.f;
#pragma unroll 8
    for(int i=0;i<DIN;i++) s2 += W_emb[d*DIN+i]*S.cur[i];
    float v = SCALE_EMB*(s2 + b_emb[d]) + pe_val(ptr, d);
    size_t idx = (size_t)(b*SEQ + ptr)*DMODEL + d;
    st_f1(h0 + idx, v);
    st_b16(h0b + idx, f2b(v));
  }
}

// ---------------- megakernel params ----------------
struct MegaP {
  const float *ln1g, *ln1b, *b1, *b2v, *ln2g, *ln2b, *Wr1, *W_emb, *b_emb, *Wr2, *br2;
  float *out;
  float *h0; unsigned short *h0b;
  float *r2, *r1;
  float *qb, *kb, *vb; unsigned short *attb, *fbuf16;
  const unsigned short *Wq16, *Wk16, *Wv16, *Wo16, *W116, *W216;
  float *M1, *cb1, *ctxt, *cur_x;
  unsigned *FL;
};

// ---------------- persistent megakernel: 22 barriers/step, RMW-free flag barrier ------
__global__ __launch_bounds__(256,1) void mega(MegaP p){
  __shared__ SmemU sm;
  const unsigned vbk = blockIdx.x;
  unsigned ep = 0;
#define GS() do{ ++ep; gsync(p.FL, ep, vbk); }while(0)

  for(int s=0;s<NSTEP;s++){
    int ptr = TH_ + s;
    for(int l=0;l<4;l++){
      const float* g2p = p.ln2g + (l-1)*DMODEL;   // only valid when l>0
      const float* b2p = p.ln2b + (l-1)*DMODEL;
      const float* g1p = p.ln1g + l*DMODEL;
      const float* b1p = p.ln1b + l*DMODEL;

      // ---- QKV (A = l==0 ? h0b : LN2(r2) fused); N=1536 scatter -> qb/kb/vb ----
      if(vbk < 96){
        int bx = (int)(vbk%12u), by = (int)(vbk/12u);
        if(l==0)
          gemm_body(bx, by, sm.g, p.h0b, DMODEL,
                    p.Wq16 + (size_t)l*262144, p.Wk16 + (size_t)l*262144, p.Wv16 + (size_t)l*262144,
                    nullptr, nullptr, nullptr, nullptr, nullptr, 0,
                    p.qb, nullptr, 0, 2, 0);
        else
          gemm_body(bx, by, sm.g, nullptr, DMODEL,
                    p.Wq16 + (size_t)l*262144, p.Wk16 + (size_t)l*262144, p.Wv16 + (size_t)l*262144,
                    nullptr, nullptr, p.r2, g2p, b2p, 1,
                    p.qb, nullptr, 0, 2, 0);
      }
      GS();

      // ---- attention (128 blocks) ----
      attn_body((int)(vbk&3u), (int)((vbk>>2)&7u), (int)(vbk>>5), sm.a, p.qb, p.kb, p.vb, p.attb);
      GS();

      // ---- Wo: att@Wo^T + (l==0 ? h0 : LN2(r2)) -> r1 fp32 (32 blocks) ----
      if(vbk < 32){
        int bx = (int)(vbk&3u), by = (int)(vbk>>2);
        if(l==0)
          gemm_body(bx, by, sm.g, p.attb, DMODEL,
                    p.Wo16 + (size_t)l*262144, nullptr, nullptr,
                    nullptr, p.h0, nullptr, nullptr, nullptr, 0,
                    p.r1, nullptr, DMODEL, 0, 0);
        else
          gemm_body(bx, by, sm.g, p.attb, DMODEL,
                    p.Wo16 + (size_t)l*262144, nullptr, nullptr,
                    nullptr, nullptr, p.r2, g2p, b2p, 2,
                    p.r1, nullptr, DMODEL, 0, 0);
      }
      GS();

      // ---- FF1: gelu(LN1(r1)@W1^T + b1) -> fbuf bf16 (128 blocks) ----
      gemm_body((int)(vbk&15u), (int)(vbk>>4), sm.g, nullptr, DMODEL,
                p.W116 + (size_t)l*1048576, nullptr, nullptr,
                p.b1 + l*DFFN, nullptr, p.r1, g1p, b1p, 1,
                nullptr, p.fbuf16, DFFN, 1, 1);
      GS();

      // ---- FF2: fbuf@W2^T + b2 + LN1(r1) -> r2 fp32 (32 blocks) ----
      if(vbk < 32)
        gemm_body((int)(vbk&3u), (int)(vbk>>2), sm.g, p.fbuf16, DFFN,
                  p.W216 + (size_t)l*1048576, nullptr, nullptr,
                  p.b2v + l*DMODEL, nullptr, p.r1, g1p, b1p, 2,
                  p.r2, nullptr, DMODEL, 0, 0);
      GS();
    }

    // ---- ctx (64 blocks) ----
    if(vbk < 64)
      ctx_body((int)(vbk&15u), (int)(vbk>>4), sm.c, p.r2,
               p.ln2g + 3*DMODEL, p.ln2b + 3*DMODEL, p.Wr1, p.cb1, p.ctxt, ptr);
    GS();

    // ---- refine + finalize + write next h0 row (4 blocks) ----
    if(vbk < 4)
      refine_body((int)vbk, sm.r, p.M1, p.ctxt, p.Wr2, p.br2, p.cur_x,
                  p.W_emb, p.b_emb, p.out, p.h0, p.h0b, s, ptr);
    GS();
  }
#undef GS
}

// ---------------- host ----------------
extern "C" void kernel_launch(void* const* d_in, const int* in_sizes, int n_in,
                              void* d_out, int out_size, void* d_ws, size_t ws_size,
                              hipStream_t stream) {
  (void)in_sizes; (void)n_in; (void)out_size; (void)ws_size;
  const float* hist = (const float*)d_in[0];
  const float* W_emb= (const float*)d_in[2];
  const float* b_emb= (const float*)d_in[3];
  const float* Wq   = (const float*)d_in[4];
  const float* Wk   = (const float*)d_in[5];
  const float* Wv   = (const float*)d_in[6];
  const float* Wo   = (const float*)d_in[7];
  const float* ln1g = (const float*)d_in[8];
  const float* ln1b = (const float*)d_in[9];
  const float* W1   = (const float*)d_in[10];
  const float* b1   = (const float*)d_in[11];
  const float* W2   = (const float*)d_in[12];
  const float* b2v  = (const float*)d_in[13];
  const float* ln2g = (const float*)d_in[14];
  const float* ln2b = (const float*)d_in[15];
  const float* Wr1  = (const float*)d_in[16];
  const float* br1  = (const float*)d_in[17];
  const float* Wr2  = (const float*)d_in[18];
  const float* br2  = (const float*)d_in[19];
  float* out = (float*)d_out;
  float* ws  = (float*)d_ws;

  const size_t BTD = (size_t)MROWS*DMODEL;      // 262144 floats
  const size_t BTDH = BTD/2;                    // bf16 buffer in float units
  float* h0   = ws;
  unsigned short* h0b = (unsigned short*)(h0 + BTD);
  float* r2   = h0 + BTD + BTDH;
  float* hln  = r2 + BTD;                       // dead (layout compat)
  float* hp   = hln + BTD;                      // reused as r1
  float* qb   = hp + BTD + BTDH;
  float* kb   = qb + BTD;
  float* vb   = kb + BTD;
  unsigned short* attb = (unsigned short*)(vb + BTD);
  unsigned short* fbuf16 = (unsigned short*)qb;   // [512][2048] bf16 (over qb/kb, dead then)
  unsigned short* W16 = (unsigned short*)(qb + 4*BTD);
  float* after_w = qb + 4*BTD + 6291456;
  float* M1   = after_w;
  float* cb1  = M1 + (size_t)DFFN*DIN;
  float* ctxt = cb1 + DFFN;
  float* cur_x= ctxt + NB*DFFN;
  unsigned* FL = (unsigned*)(cur_x + NB*DIN);   // 128 slots x 32 dwords = 16 KB

  unsigned short* Wq16 = W16;
  unsigned short* Wk16 = W16 + 1048576;
  unsigned short* Wv16 = W16 + 2097152;
  unsigned short* Wo16 = W16 + 3145728;
  unsigned short* W116 = W16 + 4194304;
  unsigned short* W216 = W16 + 8388608;

  conv_w<<<dim3(6144),dim3(256),0,stream>>>(Wq,Wk,Wv,Wo,W1,W2,W16);
  init_h0<<<dim3(MROWS),dim3(256),0,stream>>>(hist,W_emb,b_emb,h0,h0b);
  init_misc<<<dim3(256),dim3(256),0,stream>>>(Wr1,W_emb,b_emb,br1,hist,M1,cb1,cur_x,FL);

  MegaP p;
  p.ln1g=ln1g; p.ln1b=ln1b; p.b1=b1; p.b2v=b2v; p.ln2g=ln2g; p.ln2b=ln2b;
  p.Wr1=Wr1; p.W_emb=W_emb; p.b_emb=b_emb; p.Wr2=Wr2; p.br2=br2;
  p.out=out;
  p.h0=h0; p.h0b=h0b;
  p.r2=r2; p.r1=hp;
  p.qb=qb; p.kb=kb; p.vb=vb; p.attb=attb; p.fbuf16=fbuf16;
  p.Wq16=Wq16; p.Wk16=Wk16; p.Wv16=Wv16; p.Wo16=Wo16; p.W116=W116; p.W216=W216;
  p.M1=M1; p.cb1=cb1; p.ctxt=ctxt; p.cur_x=cur_x;
  p.FL=FL;

  mega<<<dim3(NBLK),dim3(256),0,stream>>>(p);
}

// Round 6
// 4995.702 us; speedup vs baseline: 1.6767x; 1.6204x over previous
//
#include <hip/hip_runtime.h>
#include <math.h>

// ---------------- problem constants ----------------
namespace {
constexpr int NB = 4;
constexpr int SEQ = 128;
constexpr int TH_ = 120;
constexpr int NSTEP = 8;
constexpr int DMODEL = 512;
constexpr int NHEAD = 8;
constexpr int DHEAD = 64;
constexpr int DFFN = 2048;
constexpr int DIN = 32;
constexpr int MROWS = NB*SEQ;   // 512 flattened rows
constexpr float SCALE_EMB = 22.627416997969522f; // sqrt(512)
constexpr float LN_EPS = 1e-5f;
constexpr float NEGF = -3.4028234663852886e38f;  // jnp.finfo(f32).min
constexpr float PE_C = -0.017988946039015984f;   // -ln(10000)/512
}

using short8 = __attribute__((ext_vector_type(8))) short;
using f32x4  = __attribute__((ext_vector_type(4))) float;

// ---------------- device helpers ----------------
__device__ __forceinline__ float wave_sum(float v){
#pragma unroll
  for(int off=32;off;off>>=1) v += __shfl_xor(v,off,64);
  return v;
}
__device__ __forceinline__ float blk_sum(float v, float* scr){
  v = wave_sum(v);
  __syncthreads();
  if((threadIdx.x&63)==0) scr[threadIdx.x>>6]=v;
  __syncthreads();
  return scr[0]+scr[1]+scr[2]+scr[3];
}
__device__ __forceinline__ float gelu_t(float x){
  float t = 0.7978845608028654f*(x + 0.044715f*x*x*x);
  return 0.5f*x*(1.0f + tanhf(t));
}
__device__ __forceinline__ float pe_val(int t, int d){
  float div = expf((float)(d & ~1) * PE_C);
  float a = (float)t * div;
  return (d & 1) ? cosf(a) : sinf(a);
}
__device__ __forceinline__ unsigned short f2b(float f){
  union { float f; unsigned u; } c; c.f = f;
  unsigned u = c.u + 0x7FFFu + ((c.u>>16)&1u);
  return (unsigned short)(u>>16);
}
__device__ __forceinline__ short8 pack8(const float* f){
  short8 s;
#pragma unroll
  for(int i=0;i<8;i++) s[i] = (short)f2b(f[i]);
  return s;
}

// ---------------- one-time: convert all weights to bf16 ----------------
__global__ __launch_bounds__(256) void conv_w(const float* __restrict__ Wq,
                                              const float* __restrict__ Wk,
                                              const float* __restrict__ Wv,
                                              const float* __restrict__ Wo,
                                              const float* __restrict__ W1,
                                              const float* __restrict__ W2,
                                              unsigned short* __restrict__ dst){
  size_t base = ((size_t)blockIdx.x*256 + threadIdx.x)*8;
  if(base >= 12582912u) return;
  const float* src; size_t off;
  if(base < 1048576u){ src=Wq; off=base; }
  else if(base < 2097152u){ src=Wk; off=base-1048576u; }
  else if(base < 3145728u){ src=Wv; off=base-2097152u; }
  else if(base < 4194304u){ src=Wo; off=base-3145728u; }
  else if(base < 8388608u){ src=W1; off=base-4194304u; }
  else { src=W2; off=base-8388608u; }
  float4 a = *(const float4*)(src+off);
  float4 b = *(const float4*)(src+off+4);
  float f[8] = {a.x,a.y,a.z,a.w,b.x,b.y,b.z,b.w};
  *(short8*)(dst + base) = pack8(f);
}

// ---------------- h0 init (fp32 + bf16) ----------------
__global__ __launch_bounds__(256) void init_h0(const float* __restrict__ hist,
                                               const float* __restrict__ W_emb,
                                               const float* __restrict__ b_emb,
                                               float* __restrict__ h0,
                                               unsigned short* __restrict__ h0b){
  int bt = blockIdx.x;
  int b = bt >> 7, t = bt & 127;
  __shared__ float x[DIN];
  if(threadIdx.x < DIN)
    x[threadIdx.x] = (t < TH_) ? hist[((size_t)b*TH_ + t)*DIN + threadIdx.x] : 0.f;
  __syncthreads();
  for(int d = threadIdx.x; d < DMODEL; d += 256){
    float s = 0.f;
#pragma unroll 8
    for(int i=0;i<DIN;i++) s += W_emb[d*DIN+i]*x[i];
    float v = SCALE_EMB*(s + b_emb[d]) + pe_val(t,d);
    h0[(size_t)bt*DMODEL + d] = v;
    h0b[(size_t)bt*DMODEL + d] = f2b(v);
  }
}

// ---------------- M1 / cb1 / cur_x init ----------------
__global__ __launch_bounds__(256) void init_misc(const float* __restrict__ Wr1,
                                                 const float* __restrict__ W_emb,
                                                 const float* __restrict__ b_emb,
                                                 const float* __restrict__ br1,
                                                 const float* __restrict__ hist,
                                                 float* __restrict__ M1,
                                                 float* __restrict__ cb1,
                                                 float* __restrict__ cur_x){
  __shared__ float row[DMODEL];
  int j0 = blockIdx.x*8;
  for(int jj=0;jj<8;jj++){
    int j = j0+jj;
    for(int k=threadIdx.x;k<DMODEL;k+=256) row[k] = Wr1[(size_t)j*1024 + k];
    __syncthreads();
    if(threadIdx.x < DIN){
      int i = threadIdx.x; float s = 0.f;
      for(int k=0;k<DMODEL;k++) s += row[k]*W_emb[k*DIN+i];
      M1[j*DIN+i] = SCALE_EMB*s;
    } else if(threadIdx.x == DIN){
      float s=0.f;
      for(int k=0;k<DMODEL;k++) s += row[k]*b_emb[k];
      cb1[j] = br1[j] + SCALE_EMB*s;
    }
    __syncthreads();
  }
  if(blockIdx.x==0 && threadIdx.x<NB*DIN){
    int b = threadIdx.x>>5, i = threadIdx.x&31;
    cur_x[b*DIN+i] = hist[((size_t)b*TH_ + (TH_-1))*DIN + i];
  }
}

// ---------------- bf16 MFMA GEMM tile 64x128, 4 waves, fused LN, reg-double-buffered --
// LNM: 0 = plain bf16 A; 1 = A operand is LN(lnx)*g+b packed bf16 on the fly;
//      2 = plain bf16 A + epilogue residual LN(lnx)*g+b.
// K-loop prefetches tile k+1 into registers while computing tile k (plain C++,
// compiler inserts counted waits). LN row stats use the exact wave-per-row
// reduction of the original lnpass kernel -> bit-identical mu/rs.
template<int LNM>
__global__ __launch_bounds__(256,1) void gemm_k(
    const unsigned short* __restrict__ A16, int Ka,
    const unsigned short* __restrict__ Wa,
    const unsigned short* __restrict__ Wb,
    const unsigned short* __restrict__ Wc,
    const float* __restrict__ bias, const float* __restrict__ resid,
    const float* __restrict__ lnx, const float* __restrict__ lng,
    const float* __restrict__ lnbta,
    float* __restrict__ Cf, unsigned short* __restrict__ Cb,
    int c_rs, int c_mode, int act)
{
  __shared__ __align__(16) unsigned short As[64][72];
  __shared__ __align__(16) unsigned short Bs[128][72];
  __shared__ float Smu[64], Srs[64];
  __shared__ float Sgs[DMODEL], Scs[DMODEL];

  int bx = blockIdx.x, by = blockIdx.y;
  int n0 = bx*128;
  int m0 = by*64;
  int tid = threadIdx.x, w = tid>>6, ln = tid&63;

  const unsigned short* Wsrc; int nrow0;
  if(c_mode==2){ int which = n0>>9; Wsrc = (which==0?Wa:(which==1?Wb:Wc)); nrow0 = n0&511; }
  else { Wsrc = Wa; nrow0 = n0; }

  // ---- LN row-stats prologue: issue all 32 loads, then reduce ----
  if constexpr(LNM != 0){
    float4 xr[16][2];
#pragma unroll
    for(int rr=0;rr<16;rr++){
      const float* xp = lnx + (size_t)(m0 + w*16 + rr)*DMODEL + ln*8;
      xr[rr][0] = *(const float4*)xp;
      xr[rr][1] = *(const float4*)(xp+4);
    }
    if constexpr(LNM==1){
      for(int k=tid;k<DMODEL;k+=256){ Sgs[k]=lng[k]; Scs[k]=lnbta[k]; }
    }
#pragma unroll
    for(int rr=0;rr<16;rr++){
      float f[8] = {xr[rr][0].x,xr[rr][0].y,xr[rr][0].z,xr[rr][0].w,
                    xr[rr][1].x,xr[rr][1].y,xr[rr][1].z,xr[rr][1].w};
      float s = 0.f;
#pragma unroll
      for(int i=0;i<8;i++) s += f[i];
      s = wave_sum(s);
      float mu = s*(1.f/DMODEL);
      float v2 = 0.f;
#pragma unroll
      for(int i=0;i<8;i++){ float d0=f[i]-mu; v2 += d0*d0; }
      v2 = wave_sum(v2);
      float rsv = rsqrtf(v2*(1.f/DMODEL) + LN_EPS);
      if(ln==0){ Smu[w*16+rr]=mu; Srs[w*16+rr]=rsv; }
    }
    __syncthreads();
  }

  f32x4 acc[4][2];
#pragma unroll
  for(int i=0;i<4;i++)
#pragma unroll
    for(int j=0;j<2;j++) acc[i][j] = (f32x4){0.f,0.f,0.f,0.f};

  int fr = ln&15, fq = (ln>>4)*8;
  int arow = tid>>2, akq = (tid&3)*16;
  int brow = tid>>1, bkq = (tid&1)*32;

  float amu=0.f, ars=0.f;
  if constexpr(LNM==1){ amu = Smu[arow]; ars = Srs[arow]; }

  // prefetch registers
  short8 a0, a1;
  float4 t0, t1, t2, t3;
  short8 b0, b1, b2, b3;

  auto LOADB = [&](int k0){
    const unsigned short* bp = Wsrc + (size_t)(nrow0+brow)*Ka + k0 + bkq;
    b0 = *(const short8*)bp;
    b1 = *(const short8*)(bp+8);
    b2 = *(const short8*)(bp+16);
    b3 = *(const short8*)(bp+24);
  };
  auto LOADA = [&](int k0){
    if constexpr(LNM==1){
      const float* fp = lnx + (size_t)(m0+arow)*DMODEL + k0 + akq;
      t0 = *(const float4*)fp;
      t1 = *(const float4*)(fp+4);
      t2 = *(const float4*)(fp+8);
      t3 = *(const float4*)(fp+12);
    } else {
      const unsigned short* ap = A16 + (size_t)(m0+arow)*Ka + k0 + akq;
      a0 = *(const short8*)ap;
      a1 = *(const short8*)(ap+8);
    }
  };

  LOADA(0); LOADB(0);
  for(int k0=0;k0<Ka;k0+=64){
    // stage current regs -> LDS (with LN transform for LNM==1)
    if constexpr(LNM==1){
      float tt[16] = {t0.x,t0.y,t0.z,t0.w, t1.x,t1.y,t1.z,t1.w,
                      t2.x,t2.y,t2.z,t2.w, t3.x,t3.y,t3.z,t3.w};
      float o[16];
#pragma unroll
      for(int i=0;i<16;i++){
        int c = k0 + akq + i;
        o[i] = (tt[i]-amu)*ars*Sgs[c] + Scs[c];
      }
      *(short8*)&As[arow][akq]   = pack8(o);
      *(short8*)&As[arow][akq+8] = pack8(o+8);
    } else {
      *(short8*)&As[arow][akq]   = a0;
      *(short8*)&As[arow][akq+8] = a1;
    }
    *(short8*)&Bs[brow][bkq]    = b0;
    *(short8*)&Bs[brow][bkq+8]  = b1;
    *(short8*)&Bs[brow][bkq+16] = b2;
    *(short8*)&Bs[brow][bkq+24] = b3;
    __syncthreads();
    // prefetch next tile while MFMAs run on this one
    if(k0+64 < Ka){ LOADA(k0+64); LOADB(k0+64); }
    short8 af[4][2], bf[2][2];
#pragma unroll
    for(int kf=0;kf<2;kf++){
#pragma unroll
      for(int rt=0;rt<4;rt++) af[rt][kf] = *(const short8*)&As[rt*16 + fr][kf*32 + fq];
#pragma unroll
      for(int ct=0;ct<2;ct++) bf[ct][kf] = *(const short8*)&Bs[32*w + ct*16 + fr][kf*32 + fq];
    }
#pragma unroll
    for(int kf=0;kf<2;kf++)
#pragma unroll
      for(int rt=0;rt<4;rt++)
#pragma unroll
        for(int ct=0;ct<2;ct++)
          acc[rt][ct] = __builtin_amdgcn_mfma_f32_16x16x32_bf16(af[rt][kf], bf[ct][kf], acc[rt][ct], 0, 0, 0);
    __syncthreads();
  }

  // ---- epilogue: batch residual loads, then compute + store ----
  float rv[4][2][4];
  const float* rsrc = (LNM==2) ? lnx : resid;
  if(rsrc){
#pragma unroll
    for(int rt=0;rt<4;rt++)
#pragma unroll
      for(int ct=0;ct<2;ct++){
        int n = n0 + 32*w + ct*16 + fr;
        int row0 = m0 + rt*16 + (ln>>4)*4;
        const float* p = rsrc + (size_t)row0*DMODEL + n;
#pragma unroll
        for(int r=0;r<4;r++) rv[rt][ct][r] = p[(size_t)r*DMODEL];
      }
  }

#pragma unroll
  for(int rt=0;rt<4;rt++){
#pragma unroll
    for(int ct=0;ct<2;ct++){
      int n = n0 + 32*w + ct*16 + fr;
      int ri0 = rt*16 + (ln>>4)*4;
      int row0 = m0 + ri0;
#pragma unroll
      for(int r=0;r<4;r++){
        int ri = ri0 + r;
        int row = row0 + r;
        float v = acc[rt][ct][r];
        if(bias)  v += bias[n];
        if constexpr(LNM==2){
          v += (rv[rt][ct][r] - Smu[ri])*Srs[ri]*lng[n] + lnbta[n];
        } else {
          if(rsrc) v += rv[rt][ct][r];
        }
        if(act==1) v = gelu_t(v);
        if(c_mode==0)      Cf[(size_t)row*c_rs + n] = v;
        else if(c_mode==1) Cb[(size_t)row*c_rs + n] = f2b(v);
        else {
          int which = n>>9, rem = n&511;
          int b = row>>7, t = row&127;
          Cf[(size_t)which*(MROWS*DMODEL) +
             ((size_t)(b*NHEAD + (rem>>6))*SEQ + t)*DHEAD + (rem&63)] = v;
        }
      }
    }
  }
}

// ---------------- fused attention per (b,h); full 128 rows; writes bf16 ---------------
__global__ __launch_bounds__(256) void attn_k(const float* __restrict__ qb,
                                              const float* __restrict__ kb,
                                              const float* __restrict__ vb,
                                              unsigned short* __restrict__ attb){
  int b = blockIdx.z, h = blockIdx.y;
  int r0 = blockIdx.x*32;
  const float* Kh = kb + (size_t)(b*NHEAD+h)*SEQ*DHEAD;
  const float* Vh = vb + (size_t)(b*NHEAD+h)*SEQ*DHEAD;
  const float* Qh = qb + (size_t)(b*NHEAD+h)*SEQ*DHEAD;
  __shared__ float kv[SEQ][DHEAD];
  __shared__ float wsm[32][132];
  __shared__ float qs[32][68];
  int tid = threadIdx.x;
  int kk = tid>>4, d4 = (tid&15)*4;

  { // K stage (xor-swizzled) + Q stage: batched float4 loads
    float4 t[8];
#pragma unroll
    for(int i=0;i<8;i++) t[i] = *(const float4*)(Kh + (size_t)(kk+16*i)*DHEAD + d4);
    float4 q0 = *(const float4*)(Qh + (size_t)(r0+kk)*DHEAD + d4);
    float4 q1 = *(const float4*)(Qh + (size_t)(r0+kk+16)*DHEAD + d4);
#pragma unroll
    for(int i=0;i<8;i++){ int k = kk+16*i; *(float4*)&kv[k][d4 ^ (k&60)] = t[i]; }
    *(float4*)&qs[kk   ][d4] = q0;
    *(float4*)&qs[kk+16][d4] = q1;
  }
  __syncthreads();

  { // logits: 2 rows x 8 keys per thread, float4 LDS reads
    int rp = tid>>4;
    int kg = tid&15;
    float acc[2][8];
#pragma unroll
    for(int i=0;i<2;i++)
#pragma unroll
      for(int kk2=0;kk2<8;kk2++) acc[i][kk2]=0.f;
#pragma unroll 4
    for(int dd=0;dd<16;dd++){
      float4 q0 = *(const float4*)&qs[2*rp][dd*4];
      float4 q1 = *(const float4*)&qs[2*rp+1][dd*4];
#pragma unroll
      for(int kk2=0;kk2<8;kk2++){
        int k = 8*kg + kk2;
        int off = (dd*4) ^ (k&60);
        float4 kv4 = *(const float4*)&kv[k][off];
        acc[0][kk2] += q0.x*kv4.x + q0.y*kv4.y + q0.z*kv4.z + q0.w*kv4.w;
        acc[1][kk2] += q1.x*kv4.x + q1.y*kv4.y + q1.z*kv4.z + q1.w*kv4.w;
      }
    }
#pragma unroll
    for(int i=0;i<2;i++){
      int t = r0 + 2*rp + i;
#pragma unroll
      for(int kk2=0;kk2<8;kk2++){
        int k = 8*kg + kk2;
        wsm[2*rp+i][k] = (k > t) ? acc[i][kk2]*0.125f : NEGF;
      }
    }
  }
  __syncthreads();

  { // softmax per row (all-masked row -> uniform 1/128, faithful to jnp)
    int l2 = tid&63, wv = tid>>6;
    for(int r=wv;r<32;r+=4){
      float l0 = wsm[r][l2], l1 = wsm[r][l2+64];
      float m = fmaxf(l0,l1);
#pragma unroll
      for(int off=32;off;off>>=1) m = fmaxf(m, __shfl_xor(m,off,64));
      float e0 = expf(l0-m), e1 = expf(l1-m);
      float s = e0+e1;
      s = wave_sum(s);
      float inv = 1.f/s;
      wsm[r][l2] = e0*inv; wsm[r][l2+64] = e1*inv;
    }
  }
  __syncthreads();

  { // V stage (overwrite kv, no swizzle): batched float4 loads
    float4 t[8];
#pragma unroll
    for(int i=0;i<8;i++) t[i] = *(const float4*)(Vh + (size_t)(kk+16*i)*DHEAD + d4);
#pragma unroll
    for(int i=0;i<8;i++) *(float4*)&kv[kk+16*i][d4] = t[i];
  }
  __syncthreads();

  { // out = w @ V, pack bf16
    int dq = (tid&15)*4, rg = tid>>4;
    for(int r=rg;r<32;r+=16){
      float4 acc2 = make_float4(0.f,0.f,0.f,0.f);
      for(int k=0;k<SEQ;k++){
        float w0 = wsm[r][k];
        float4 v = *(const float4*)&kv[k][dq];
        acc2.x += w0*v.x; acc2.y += w0*v.y; acc2.z += w0*v.z; acc2.w += w0*v.w;
      }
      int row = b*SEQ + r0 + r;
      unsigned short* op = attb + (size_t)row*DMODEL + h*DHEAD + dq;
      op[0]=f2b(acc2.x); op[1]=f2b(acc2.y); op[2]=f2b(acc2.z); op[3]=f2b(acc2.w);
    }
  }
}

// ---------------- ctx = LN2_3(r2[ptr-1]); ctxt = Wr1b@ctx + cb1 -----------------------
__global__ __launch_bounds__(256) void ctx_k(const float* __restrict__ r2,
                                             const float* __restrict__ g2,
                                             const float* __restrict__ b2,
                                             const float* __restrict__ Wr1,
                                             const float* __restrict__ cb1,
                                             float* __restrict__ ctxt, int ptr){
  int b = blockIdx.y; int j0 = blockIdx.x*128;
  __shared__ float raw[DMODEL], ctx[DMODEL], scr[4];
  int tid = threadIdx.x;
  const float* rp = r2 + (size_t)(b*SEQ + ptr-1)*DMODEL;
  for(int k=tid;k<DMODEL;k+=256) raw[k]=rp[k];
  __syncthreads();
  float s = 0.f;
  for(int k=tid;k<DMODEL;k+=256) s += raw[k];
  s = blk_sum(s, scr);
  float mu = s/(float)DMODEL;
  float v = 0.f;
  for(int k=tid;k<DMODEL;k+=256){ float d0 = raw[k]-mu; v += d0*d0; }
  v = blk_sum(v, scr);
  float rs = rsqrtf(v/(float)DMODEL + LN_EPS);
  for(int k=tid;k<DMODEL;k+=256) ctx[k] = (raw[k]-mu)*rs*g2[k] + b2[k];
  __syncthreads();
  int wv = tid>>6, l2 = tid&63;
  for(int jj=wv;jj<128;jj+=4){
    int j = j0+jj;
    const float* wp = Wr1 + (size_t)j*1024 + 512;
    float acc = 0.f;
#pragma unroll
    for(int q=0;q<8;q++){ int k = l2 + 64*q; acc += wp[k]*ctx[k]; }
    acc = wave_sum(acc);
    if(l2==0) ctxt[b*DFFN + j] = acc + cb1[j];
  }
}

// ---------------- fused refine (5 substeps) + finalize, one wg per batch --------------
__global__ __launch_bounds__(256) void refine_fin(const float* __restrict__ M1,
                                                  const float* __restrict__ ctxt,
                                                  const float* __restrict__ Wr2,
                                                  const float* __restrict__ br2,
                                                  float* __restrict__ cur_x,
                                                  const float* __restrict__ W_emb,
                                                  const float* __restrict__ b_emb,
                                                  float* __restrict__ out,
                                                  float* __restrict__ h0,
                                                  unsigned short* __restrict__ h0b,
                                                  int s, int ptr){
  int b = blockIdx.x, tid = threadIdx.x;
  __shared__ float cur[DIN], gs[DFFN], dscr[DIN];
  if(tid < DIN) cur[tid] = cur_x[b*DIN + tid];
  __syncthreads();
  for(int sub=0; sub<5; sub++){
    for(int jj=tid; jj<DFFN; jj+=256){
      float u = ctxt[b*DFFN + jj];
      const float* mp = M1 + (size_t)jj*DIN;
#pragma unroll
      for(int p=0;p<8;p++){
        float4 mv = *(const float4*)(mp + 4*p);
        u += mv.x*cur[4*p] + mv.y*cur[4*p+1] + mv.z*cur[4*p+2] + mv.w*cur[4*p+3];
      }
      gs[jj] = gelu_t(u);
    }
    __syncthreads();
    int w = tid>>6, l = tid&63;
#pragma unroll
    for(int q=0;q<8;q++){
      int i = w*8 + q;
      const float* wr = Wr2 + (size_t)i*DFFN;
      float a = 0.f;
#pragma unroll
      for(int p=0;p<8;p++){
        int j0 = p*256 + l*4;
        float4 wv = *(const float4*)(wr + j0);
        float4 gv = *(const float4*)&gs[j0];
        a += wv.x*gv.x + wv.y*gv.y + wv.z*gv.z + wv.w*gv.w;
      }
      a = wave_sum(a);
      if(l==0) dscr[i] = a;
    }
    __syncthreads();
    if(tid < DIN) cur[tid] += dscr[tid] + br2[tid];
    __syncthreads();
  }
  if(tid < DIN){
    out[(b*NSTEP + s)*DIN + tid] = cur[tid];
    cur_x[b*DIN + tid] = cur[tid];
  }
  __syncthreads();
  for(int d=tid; d<DMODEL; d+=256){
    float s2 = 0.f;
#pragma unroll 8
    for(int i=0;i<DIN;i++) s2 += W_emb[d*DIN+i]*cur[i];
    float v = SCALE_EMB*(s2 + b_emb[d]) + pe_val(ptr, d);
    size_t idx = (size_t)(b*SEQ + ptr)*DMODEL + d;
    h0[idx] = v;
    h0b[idx] = f2b(v);
  }
}

// ---------------- host ----------------
extern "C" void kernel_launch(void* const* d_in, const int* in_sizes, int n_in,
                              void* d_out, int out_size, void* d_ws, size_t ws_size,
                              hipStream_t stream) {
  (void)in_sizes; (void)n_in; (void)out_size; (void)ws_size;
  const float* hist = (const float*)d_in[0];
  const float* W_emb= (const float*)d_in[2];
  const float* b_emb= (const float*)d_in[3];
  const float* Wq   = (const float*)d_in[4];
  const float* Wk   = (const float*)d_in[5];
  const float* Wv   = (const float*)d_in[6];
  const float* Wo   = (const float*)d_in[7];
  const float* ln1g = (const float*)d_in[8];
  const float* ln1b = (const float*)d_in[9];
  const float* W1   = (const float*)d_in[10];
  const float* b1   = (const float*)d_in[11];
  const float* W2   = (const float*)d_in[12];
  const float* b2v  = (const float*)d_in[13];
  const float* ln2g = (const float*)d_in[14];
  const float* ln2b = (const float*)d_in[15];
  const float* Wr1  = (const float*)d_in[16];
  const float* br1  = (const float*)d_in[17];
  const float* Wr2  = (const float*)d_in[18];
  const float* br2  = (const float*)d_in[19];
  float* out = (float*)d_out;
  float* ws  = (float*)d_ws;

  const size_t BTD = (size_t)MROWS*DMODEL;      // 262144 floats
  const size_t BTDH = BTD/2;                    // bf16 buffer in float units
  float* h0   = ws;
  unsigned short* h0b = (unsigned short*)(h0 + BTD);
  float* r2   = h0 + BTD + BTDH;
  float* hln  = r2 + BTD;                       // dead (layout compat)
  float* hp   = hln + BTD;                      // reused as r1 (pre-LN1 residual)
  float* qb   = hp + BTD + BTDH;
  float* kb   = qb + BTD;
  float* vb   = kb + BTD;
  unsigned short* attb = (unsigned short*)(vb + BTD);
  unsigned short* fbuf16 = (unsigned short*)qb;   // [512][2048] bf16 (over qb/kb, dead then)
  float* r1   = hp;
  unsigned short* W16 = (unsigned short*)(qb + 4*BTD);
  float* after_w = qb + 4*BTD + 6291456;
  float* M1   = after_w;
  float* cb1  = M1 + (size_t)DFFN*DIN;
  float* ctxt = cb1 + DFFN;
  float* cur_x= ctxt + NB*DFFN;

  unsigned short* Wq16 = W16;
  unsigned short* Wk16 = W16 + 1048576;
  unsigned short* Wv16 = W16 + 2097152;
  unsigned short* Wo16 = W16 + 3145728;
  unsigned short* W116 = W16 + 4194304;
  unsigned short* W216 = W16 + 8388608;

  conv_w<<<dim3(6144),dim3(256),0,stream>>>(Wq,Wk,Wv,Wo,W1,W2,W16);
  init_h0<<<dim3(MROWS),dim3(256),0,stream>>>(hist,W_emb,b_emb,h0,h0b);
  init_misc<<<dim3(256),dim3(256),0,stream>>>(Wr1,W_emb,b_emb,br1,hist,M1,cb1,cur_x);

  for(int s=0;s<NSTEP;s++){
    int ptr = TH_ + s;
    for(int l=0;l<4;l++){
      const float* g2p = ln2g + (l-1)*DMODEL;   // only valid when l>0
      const float* b2p = ln2b + (l-1)*DMODEL;
      const float* g1p = ln1g + l*DMODEL;
      const float* b1p = ln1b + l*DMODEL;

      // QKV (A = l==0 ? h0b : LN2(r2) fused); N=1536 scatter -> qb/kb/vb
      if(l==0)
        gemm_k<0><<<dim3(12,8),dim3(256),0,stream>>>(h0b, DMODEL,
            Wq16 + (size_t)l*262144, Wk16 + (size_t)l*262144, Wv16 + (size_t)l*262144,
            nullptr, nullptr, nullptr, nullptr, nullptr,
            qb, nullptr, 0, 2, 0);
      else
        gemm_k<1><<<dim3(12,8),dim3(256),0,stream>>>(nullptr, DMODEL,
            Wq16 + (size_t)l*262144, Wk16 + (size_t)l*262144, Wv16 + (size_t)l*262144,
            nullptr, nullptr, r2, g2p, b2p,
            qb, nullptr, 0, 2, 0);

      attn_k<<<dim3(4,NHEAD,NB),dim3(256),0,stream>>>(qb,kb,vb,attb);

      // Wo: att@Wo^T + (l==0 ? h0 : LN2(r2)) -> r1 fp32
      if(l==0)
        gemm_k<0><<<dim3(4,8),dim3(256),0,stream>>>(attb, DMODEL,
            Wo16 + (size_t)l*262144, nullptr, nullptr,
            nullptr, h0, nullptr, nullptr, nullptr,
            r1, nullptr, DMODEL, 0, 0);
      else
        gemm_k<2><<<dim3(4,8),dim3(256),0,stream>>>(attb, DMODEL,
            Wo16 + (size_t)l*262144, nullptr, nullptr,
            nullptr, nullptr, r2, g2p, b2p,
            r1, nullptr, DMODEL, 0, 0);

      // FF1: gelu(LN1(r1)@W1^T + b1) -> fbuf bf16
      gemm_k<1><<<dim3(16,8),dim3(256),0,stream>>>(nullptr, DMODEL,
          W116 + (size_t)l*1048576, nullptr, nullptr,
          b1 + l*DFFN, nullptr, r1, g1p, b1p,
          nullptr, fbuf16, DFFN, 1, 1);

      // FF2: fbuf@W2^T + b2 + LN1(r1) -> r2 fp32
      gemm_k<2><<<dim3(4,8),dim3(256),0,stream>>>(fbuf16, DFFN,
          W216 + (size_t)l*1048576, nullptr, nullptr,
          b2v + l*DMODEL, nullptr, r1, g1p, b1p,
          r2, nullptr, DMODEL, 0, 0);
    }

    ctx_k<<<dim3(16,NB),dim3(256),0,stream>>>(r2, ln2g + 3*DMODEL, ln2b + 3*DMODEL,
                                              Wr1, cb1, ctxt, ptr);
    refine_fin<<<dim3(NB),dim3(256),0,stream>>>(M1, ctxt, Wr2, br2, cur_x,
                                                W_emb, b_emb, out, h0, h0b, s, ptr);
  }
}